// Round 3
// baseline (576.094 us; speedup 1.0000x reference)
//
#include <hip/hip_runtime.h>

typedef unsigned short u16;
typedef __attribute__((ext_vector_type(8))) unsigned short u16x8;
typedef __attribute__((ext_vector_type(4))) unsigned short u16x4;
typedef __attribute__((ext_vector_type(4))) float f32x4;

#define DEVI __device__ __forceinline__

// ---------------- helpers ----------------
DEVI u16 f2bf(float f){
  unsigned u = __float_as_uint(f);
  u += 0x7FFFu + ((u >> 16) & 1u);      // round-to-nearest-even
  return (u16)(u >> 16);
}

DEVI void gload16(const void* g, void* l){
  __builtin_amdgcn_global_load_lds((const __attribute__((address_space(1))) void*)g,
                                   (__attribute__((address_space(3))) void*)l, 16, 0, 0);
}

DEVI float wave_sum(float v){
#pragma unroll
  for (int o = 32; o; o >>= 1) v += __shfl_xor(v, o, 64);
  return v;
}

#define MFMA16(a,b,c) __builtin_amdgcn_mfma_f32_16x16x32_bf16((a),(b),(c),0,0,0)

// ---------------- elementwise convert f32 -> bf16 ----------------
__global__ __launch_bounds__(256) void f32_to_bf16_k(const float* __restrict__ in,
                                                     u16* __restrict__ out, int n4){
  int i = blockIdx.x * 256 + threadIdx.x;
  if (i < n4){
    float4 v = ((const float4*)in)[i];
    u16x4 o = { f2bf(v.x), f2bf(v.y), f2bf(v.z), f2bf(v.w) };
    ((u16x4*)out)[i] = o;
  }
}

// ---------------- transpose f32 [R][C] -> bf16 [C][R], z-batched ----------------
__global__ __launch_bounds__(256) void trans_f32_bf16_k(const float* __restrict__ in0,
                                                        u16* __restrict__ out0, int R, int C){
  __shared__ u16 tile[32][33];
  const float* in = in0 + (size_t)blockIdx.z * R * C;
  u16* out = out0 + (size_t)blockIdx.z * R * C;
  const int c0 = blockIdx.x * 32, r0 = blockIdx.y * 32;
  const int tx = threadIdx.x & 31, ty = threadIdx.x >> 5;
#pragma unroll
  for (int k = 0; k < 4; k++)
    tile[ty + k*8][tx] = f2bf(in[(size_t)(r0 + ty + k*8) * C + c0 + tx]);
  __syncthreads();
#pragma unroll
  for (int k = 0; k < 4; k++)
    out[(size_t)(c0 + ty + k*8) * R + r0 + tx] = tile[tx][ty + k*8];
}

// ---------------- V transpose: bf16 [B*T][N*H] -> [B][N][H][T] ----------------
__global__ __launch_bounds__(256) void vtrans_k(const u16* __restrict__ V, u16* __restrict__ Vt){
  __shared__ u16 tile[32][33];
  const int t0 = blockIdx.x * 32;
  const int h0 = blockIdx.y * 32;
  const int bn = blockIdx.z; const int b = bn >> 4, n = bn & 15;
  const int tx = threadIdx.x & 31, ty = threadIdx.x >> 5;
#pragma unroll
  for (int k = 0; k < 4; k++)
    tile[ty + k*8][tx] = V[(size_t)(b*512 + t0 + ty + k*8) * 1024 + n*64 + h0 + tx];
  __syncthreads();
#pragma unroll
  for (int k = 0; k < 4; k++)
    Vt[(size_t)((b*16 + n)*64 + h0 + ty + k*8) * 512 + t0 + tx] = tile[tx][ty + k*8];
}

// ---------------- layernorm: rows of 1024, (x-m)/(std+eps) ----------------
template<int OUTF32>
__global__ __launch_bounds__(256) void layernorm_k(const float* __restrict__ in, void* __restrict__ outp){
  const int row = blockIdx.x;
  const int tid = threadIdx.x;
  const float4 v = ((const float4*)(in + (size_t)row * 1024))[tid];
  __shared__ float sb[8];
  const int wid = tid >> 6, lane = tid & 63;
  float s = wave_sum(v.x + v.y + v.z + v.w);
  if (lane == 0) sb[wid] = s;
  __syncthreads();
  const float mean = (sb[0] + sb[1] + sb[2] + sb[3]) * (1.0f / 1024.0f);
  const float dx = v.x - mean, dy = v.y - mean, dz = v.z - mean, dw = v.w - mean;
  float q = wave_sum(dx*dx + dy*dy + dz*dz + dw*dw);
  if (lane == 0) sb[4 + wid] = q;
  __syncthreads();
  const float sd = sqrtf((sb[4] + sb[5] + sb[6] + sb[7]) * (1.0f / 1024.0f));
  const float inv = 1.0f / (sd + 1e-6f);
  if (OUTF32){
    ((float4*)outp)[(size_t)row * 256 + tid] = make_float4(dx*inv, dy*inv, dz*inv, dw*inv);
  } else {
    u16x4 o = { f2bf(dx*inv), f2bf(dy*inv), f2bf(dz*inv), f2bf(dw*inv) };
    ((u16x4*)outp)[(size_t)row * 256 + tid] = o;
  }
}

// ---------------- time-bias MLP: qs[b,f,t] ----------------
__global__ __launch_bounds__(256) void qsbias_k(const float* __restrict__ dist,
    const float* __restrict__ Wth, const float* __restrict__ bth,
    const float* __restrict__ Wto, const float* __restrict__ bto,
    float* __restrict__ qs){
  const int idx = blockIdx.x * 256 + threadIdx.x;        // over B*F*T/4
  float4 s4 = ((const float4*)dist)[idx];
  float sv[4] = { s4.x, s4.y, s4.z, s4.w };
  float r[4];
  const float b0 = bto[0];
#pragma unroll
  for (int c = 0; c < 4; c++) r[c] = b0;
#pragma unroll
  for (int k = 0; k < 32; k++){
    const float wk = Wth[k], bk = bth[k], ok = Wto[k];
#pragma unroll
    for (int c = 0; c < 4; c++){
      float h = fmaxf(sv[c] * wk + bk, 0.0f);
      r[c] += h * ok;
    }
  }
  ((float4*)qs)[idx] = make_float4(r[0], r[1], r[2], r[3]);
}

// ---------------- 128x128 GEMM core, BK=64, 2-phase LDS double-buffer ---------
// C[M][Nd] = A[M][Kd-range] @ Bt[Nd][Kd-range]^T. 4 waves (2x2), each 64x64.
// T2 swizzle: linear gload_lds dest + inverse-swizzled global source chunk,
// reads XOR back (rule 21). MODE 0: bf16  1: bf16*scale  2: f32+resid
// MODE 3: bf16 relu(+bias)  5: f32 partial
template<int MODE>
DEVI void gemm128_core(const u16* A, int lda, const u16* Bt, int ldb,
                       int Klen, int Nd, void* Cout,
                       const float* bias, const float* resid, float scale,
                       u16* Als, u16* Bls, int row0, int col0){
  const int tid = threadIdx.x;
  const int wid = tid >> 6, lane = tid & 63;
  const int wm = wid >> 1, wn = wid & 1;
  const int lrow = lane & 15, g = lane >> 4, e7 = lane & 7;
  f32x4 acc[4][4] = {};

  const int scol = ((lane & 7) ^ ((lane >> 3) & 7)) * 8;   // inverse-swizzled src chunk
  const u16* Ag = A + (size_t)(row0 + wid*8 + (lane >> 3)) * lda + scol;
  const u16* Bg = Bt + (size_t)(col0 + wid*8 + (lane >> 3)) * ldb + scol;
  const int dst0 = wid * 512;

  const int nt = Klen >> 6;

#define STAGE128(buf, k0)                                                     \
  {                                                                           \
    _Pragma("unroll")                                                         \
    for (int q = 0; q < 4; q++){                                              \
      gload16(Ag + (size_t)q*32*lda + (k0), Als + (buf)*8192 + dst0 + q*2048);\
      gload16(Bg + (size_t)q*32*ldb + (k0), Bls + (buf)*8192 + dst0 + q*2048);\
    }                                                                         \
  }

  STAGE128(0, 0);
  __syncthreads();                       // compiler drains vmcnt before barrier

  for (int t = 0; t < nt; t++){
    const int cur = t & 1;
    if (t + 1 < nt) STAGE128(cur ^ 1, (t + 1) << 6);   // prefetch overlaps MFMA
    const u16* Ab = Als + cur * 8192;
    const u16* Bb = Bls + cur * 8192;
#pragma unroll
    for (int ks = 0; ks < 2; ks++){
      const int sl = (((ks << 2) + g) ^ e7) << 3;
      u16x8 av[4], bv[4];
#pragma unroll
      for (int mi = 0; mi < 4; mi++)
        av[mi] = *(const u16x8*)(Ab + (wm*64 + mi*16 + lrow) * 64 + sl);
#pragma unroll
      for (int ni = 0; ni < 4; ni++)
        bv[ni] = *(const u16x8*)(Bb + (wn*64 + ni*16 + lrow) * 64 + sl);
#pragma unroll
      for (int mi = 0; mi < 4; mi++)
#pragma unroll
        for (int ni = 0; ni < 4; ni++)
          acc[mi][ni] = MFMA16(av[mi], bv[ni], acc[mi][ni]);
    }
    __syncthreads();
  }
#undef STAGE128

#pragma unroll
  for (int mi = 0; mi < 4; mi++){
#pragma unroll
    for (int ni = 0; ni < 4; ni++){
      const int col = col0 + wn*64 + ni*16 + lrow;
#pragma unroll
      for (int j = 0; j < 4; j++){
        const int row = row0 + wm*64 + mi*16 + g*4 + j;
        float v = acc[mi][ni][j];
        if (MODE == 1) v *= scale;
        if (MODE == 3) v = fmaxf(v + bias[col], 0.0f);
        if (MODE == 2) v = v + resid[(size_t)row * Nd + col];
        if (MODE == 0 || MODE == 1 || MODE == 3)
          ((u16*)Cout)[(size_t)row * Nd + col] = f2bf(v);
        else
          ((float*)Cout)[(size_t)row * Nd + col] = v;
      }
    }
  }
}

template<int MODE>
__global__ __launch_bounds__(256) void gemm128_k(const u16* __restrict__ A, int lda,
    const u16* __restrict__ Bt, int ldb, int Klen, int Nd, void* __restrict__ Cout,
    const float* __restrict__ bias, const float* __restrict__ resid, float scale){
  __shared__ __align__(16) u16 Als[2 * 8192];
  __shared__ __align__(16) u16 Bls[2 * 8192];
  gemm128_core<MODE>(A, lda, Bt, ldb, Klen, Nd, Cout, bias, resid, scale,
                     Als, Bls, blockIdx.y * 128, blockIdx.x * 128);
}

// K,V,Q projections in one dispatch (z selects), grid (8,8,3)
__global__ __launch_bounds__(256) void gemmQKV_k(
    const u16* __restrict__ encb, const u16* __restrict__ Wkt, u16* __restrict__ Kb,
    const u16* __restrict__ Wvt, u16* __restrict__ Vb,
    const u16* __restrict__ xn, const u16* __restrict__ Wqt, u16* __restrict__ Qb){
  __shared__ __align__(16) u16 Als[2 * 8192];
  __shared__ __align__(16) u16 Bls[2 * 8192];
  const int r0 = blockIdx.y * 128, c0 = blockIdx.x * 128;
  const int z = blockIdx.z;
  if (z == 0)
    gemm128_core<0>(encb, 1024, Wkt, 1024, 1024, 1024, Kb, nullptr, nullptr, 1.0f, Als, Bls, r0, c0);
  else if (z == 1)
    gemm128_core<0>(encb, 1024, Wvt, 1024, 1024, 1024, Vb, nullptr, nullptr, 1.0f, Als, Bls, r0, c0);
  else
    gemm128_core<1>(xn, 1024, Wqt, 1024, 1024, 1024, Qb, nullptr, nullptr, 0.125f, Als, Bls, r0, c0);
}

// FFN2 split-K: grid (8,8,4), K=4096 split into 4x1024, f32 partials
__global__ __launch_bounds__(256) void gemm_splitk_k(const u16* __restrict__ A, int lda,
    const u16* __restrict__ Bt, int ldb, float* __restrict__ part){
  __shared__ __align__(16) u16 Als[2 * 8192];
  __shared__ __align__(16) u16 Bls[2 * 8192];
  const int z = blockIdx.z;
  gemm128_core<5>(A + z * 1024, lda, Bt + z * 1024, ldb, 1024, 1024,
                  part + (size_t)z * 1024 * 1024, nullptr, nullptr, 1.0f,
                  Als, Bls, blockIdx.y * 128, blockIdx.x * 128);
}

// x += bias[col] + sum of 4 partials
__global__ __launch_bounds__(256) void reduce_ffn2_k(const float* __restrict__ part,
    const float* __restrict__ bias, float* __restrict__ x){
  const int idx = blockIdx.x * 256 + threadIdx.x;      // f32x4 groups over 1024x1024
  const int col = (idx * 4) & 1023;
  float4 a = ((const float4*)x)[idx];
  const float4 b = *(const float4*)(bias + col);
  float4 p0 = ((const float4*)part)[idx];
  float4 p1 = ((const float4*)(part + 1048576))[idx];
  float4 p2 = ((const float4*)(part + 2097152))[idx];
  float4 p3 = ((const float4*)(part + 3145728))[idx];
  a.x += b.x + p0.x + p1.x + p2.x + p3.x;
  a.y += b.y + p0.y + p1.y + p2.y + p3.y;
  a.z += b.z + p0.z + p1.z + p2.z + p3.z;
  a.w += b.w + p0.w + p1.w + p2.w + p3.w;
  ((float4*)x)[idx] = a;
}

// ---------------- fused flash attention ----------------
// grid (n=16, ftile=8, b=2); 4 waves, wave w owns 16 q-rows.
// S^T = mfma(K, Q^T): lane holds S[fw+l15][t]; softmax row is lane-local in l15.
// P -> per-wave LDS (swizzled), PV = mfma(P, V^T) with V^T frags from L2.
__global__ __launch_bounds__(256, 1) void attn_k(const u16* __restrict__ Q,
    const u16* __restrict__ Kb, const u16* __restrict__ Vt,
    const float* __restrict__ qs, const float* __restrict__ abias,
    u16* __restrict__ aout){
  const int n = blockIdx.x, f0 = blockIdx.y * 64, b = blockIdx.z;
  const int w = threadIdx.x >> 6, lane = threadIdx.x & 63;
  const int l15 = lane & 15, g = lane >> 4, e7 = lane & 7;
  const int fw = f0 + w * 16;
  __shared__ __align__(16) u16 Pl[4][16 * 512];   // 64 KB, per-wave private
  u16* pw = &Pl[w][0];

  // Q fragments (B-operand): lane holds Q[fw+l15][k]
  const u16* qp = Q + ((size_t)b*512 + fw + l15) * 1024 + n*64 + g*8;
  const u16x8 qf0 = *(const u16x8*)qp;
  const u16x8 qf1 = *(const u16x8*)(qp + 32);

  // QK^T: acc[tf] holds S[fw+l15][tf*16 + g*4 + j]
  f32x4 acc[32];
  const u16* kp = Kb + ((size_t)b*512 + l15) * 1024 + n*64 + g*8;
#pragma unroll
  for (int tf = 0; tf < 32; tf++){
    u16x8 k0 = *(const u16x8*)(kp + (size_t)tf*16*1024);
    u16x8 k1 = *(const u16x8*)(kp + (size_t)tf*16*1024 + 32);
    f32x4 z = {0.f, 0.f, 0.f, 0.f};
    z = MFMA16(k0, qf0, z);
    acc[tf] = MFMA16(k1, qf1, z);
  }

  // + qs bias + attn bias, row max
  const float* qsp = qs + ((size_t)b*512 + fw + l15) * 512 + g*4;
  const float* abp = abias + (size_t)b*512 + g*4;
  float m = -3.0e38f;
#pragma unroll
  for (int tf = 0; tf < 32; tf++){
    float4 qv = *(const float4*)(qsp + tf*16);
    float4 av = *(const float4*)(abp + tf*16);
    acc[tf][0] += qv.x + av.x;
    acc[tf][1] += qv.y + av.y;
    acc[tf][2] += qv.z + av.z;
    acc[tf][3] += qv.w + av.w;
    m = fmaxf(m, fmaxf(fmaxf(acc[tf][0], acc[tf][1]), fmaxf(acc[tf][2], acc[tf][3])));
  }
  m = fmaxf(m, __shfl_xor(m, 16, 64));
  m = fmaxf(m, __shfl_xor(m, 32, 64));

  float s = 0.f;
#pragma unroll
  for (int tf = 0; tf < 32; tf++){
#pragma unroll
    for (int j = 0; j < 4; j++){
      float e = __expf(acc[tf][j] - m);
      acc[tf][j] = e; s += e;
    }
  }
  s += __shfl_xor(s, 16, 64);
  s += __shfl_xor(s, 32, 64);
  const float inv = 1.0f / s;
  float invj[4];
#pragma unroll
  for (int j = 0; j < 4; j++) invj[j] = __shfl(inv, g*4 + j, 64);  // inv for row g*4+j

  // store unnormalized P (<=1) row-major [16][512] bf16, chunk-swizzled
#pragma unroll
  for (int tf = 0; tf < 32; tf++){
    const int chunk = tf*2 + (g >> 1);
    const int boff = (l15 << 10) + ((chunk ^ e7) << 4) + ((g & 1) << 3);
    u16x4 pk = { f2bf(acc[tf][0]), f2bf(acc[tf][1]), f2bf(acc[tf][2]), f2bf(acc[tf][3]) };
    *(u16x4*)((char*)pw + boff) = pk;
  }

  // PV: O[f][h] = P[f][:] @ V[:][h];  V^T frags direct from global (L2-resident)
  f32x4 oacc[4] = {};
  const u16* vp = Vt + ((size_t)(b*16 + n)*64 + l15) * 512 + g*8;
  for (int kk = 0; kk < 16; kk++){
    u16x8 pa = *(const u16x8*)((char*)pw + (l15 << 10) + ((((kk << 2) + g) ^ e7) << 4));
#pragma unroll
    for (int nf = 0; nf < 4; nf++){
      u16x8 vb = *(const u16x8*)(vp + (size_t)nf*16*512 + kk*32);
      oacc[nf] = MFMA16(pa, vb, oacc[nf]);
    }
  }

  u16* op = aout + ((size_t)b*512 + fw + g*4) * 1024 + n*64 + l15;
#pragma unroll
  for (int nf = 0; nf < 4; nf++)
#pragma unroll
    for (int j = 0; j < 4; j++)
      op[(size_t)j*1024 + nf*16] = f2bf(oacc[nf][j] * invj[j]);
}

// ---------------- host ----------------
extern "C" void kernel_launch(void* const* d_in, const int* in_sizes, int n_in,
                              void* d_out, int out_size, void* d_ws, size_t ws_size,
                              hipStream_t stream){
  const float* dec_in   = (const float*)d_in[0];
  const float* enc      = (const float*)d_in[1];
  const float* dist     = (const float*)d_in[3];
  const float* abias    = (const float*)d_in[5];
  const float* Wq  = (const float*)d_in[6];
  const float* Wk  = (const float*)d_in[7];
  const float* Wv  = (const float*)d_in[8];
  const float* Wo  = (const float*)d_in[9];
  const float* Wth = (const float*)d_in[10];
  const float* bth = (const float*)d_in[11];
  const float* Wto = (const float*)d_in[12];
  const float* bto = (const float*)d_in[13];
  const float* Wf1 = (const float*)d_in[14];
  const float* bf1 = (const float*)d_in[15];
  const float* Wf2 = (const float*)d_in[16];
  const float* bf2 = (const float*)d_in[17];
  float* dout = (float*)d_out;

  char* wp = (char*)d_ws;
  auto alloc = [&](size_t n) -> char* {
    char* p = wp; wp += (n + 255) & ~(size_t)255; return p;
  };
  float* x     = (float*)alloc((size_t)1048576 * 4);
  u16*  xn     = (u16*)alloc((size_t)1048576 * 2);
  u16*  encb   = (u16*)alloc((size_t)1048576 * 2);
  u16*  Wqt    = (u16*)alloc((size_t)4194304 * 2);   // 4 layers
  u16*  Wkt    = (u16*)alloc((size_t)4194304 * 2);
  u16*  Wvt    = (u16*)alloc((size_t)4194304 * 2);
  u16*  Wot    = (u16*)alloc((size_t)4194304 * 2);
  u16*  Wf1t   = (u16*)alloc((size_t)4194304 * 2);   // per-layer reuse
  u16*  Wf2t   = (u16*)alloc((size_t)4194304 * 2);
  u16*  Kb     = (u16*)alloc((size_t)1048576 * 2);
  u16*  Vb     = (u16*)alloc((size_t)1048576 * 2);
  u16*  Vt     = (u16*)alloc((size_t)1048576 * 2);
  u16*  Qb     = (u16*)alloc((size_t)1048576 * 2);
  float* qs    = (float*)alloc((size_t)524288 * 4);
  u16*  aout   = (u16*)alloc((size_t)1048576 * 2);
  u16*  ffh    = (u16*)alloc((size_t)4194304 * 2);
  float* part  = (float*)alloc((size_t)4194304 * 4);  // 4x 1024x1024 f32

  hipMemcpyAsync(x, dec_in, (size_t)1048576 * 4, hipMemcpyDeviceToDevice, stream);
  f32_to_bf16_k<<<1024, 256, 0, stream>>>(enc, encb, 262144);

  // all QKVO weight transposes upfront, z-batched over layers
  trans_f32_bf16_k<<<dim3(32, 32, 4), 256, 0, stream>>>(Wq, Wqt, 1024, 1024);
  trans_f32_bf16_k<<<dim3(32, 32, 4), 256, 0, stream>>>(Wk, Wkt, 1024, 1024);
  trans_f32_bf16_k<<<dim3(32, 32, 4), 256, 0, stream>>>(Wv, Wvt, 1024, 1024);
  trans_f32_bf16_k<<<dim3(32, 32, 4), 256, 0, stream>>>(Wo, Wot, 1024, 1024);

  for (int i = 0; i < 4; i++){
    const size_t wo = (size_t)i * 1048576;
    trans_f32_bf16_k<<<dim3(128, 32), 256, 0, stream>>>(Wf1 + (size_t)i*4194304, Wf1t, 1024, 4096);
    trans_f32_bf16_k<<<dim3(32, 128), 256, 0, stream>>>(Wf2 + (size_t)i*4194304, Wf2t, 4096, 1024);

    qsbias_k<<<512, 256, 0, stream>>>(dist, Wth + i*32, bth + i*32, Wto + i*32, bto + i, qs);

    // pre-norm, then K/V/Q projections batched (192 blocks, 128^2 tiles)
    layernorm_k<0><<<1024, 256, 0, stream>>>(x, xn);
    gemmQKV_k<<<dim3(8, 8, 3), 256, 0, stream>>>(encb, Wkt + wo, Kb, Wvt + wo, Vb, xn, Wqt + wo, Qb);
    vtrans_k<<<dim3(16, 2, 32), 256, 0, stream>>>(Vb, Vt);

    // fused attention (logits + biases + softmax + PV)
    attn_k<<<dim3(16, 8, 2), 256, 0, stream>>>(Qb, Kb, Vt, qs, abias, aout);

    // output projection + residual (x updated in place)
    gemm128_k<2><<<dim3(8, 8), 256, 0, stream>>>(aout, 1024, Wot + wo, 1024, 1024, 1024, x,
                                                 nullptr, x, 1.0f);

    // FFN
    layernorm_k<0><<<1024, 256, 0, stream>>>(x, xn);
    gemm128_k<3><<<dim3(32, 8), 256, 0, stream>>>(xn, 1024, Wf1t, 1024, 1024, 4096, ffh,
                                                  bf1 + (size_t)i*4096, nullptr, 1.0f);
    gemm_splitk_k<<<dim3(8, 8, 4), 256, 0, stream>>>(ffh, 4096, Wf2t, 4096, part);
    reduce_ffn2_k<<<1024, 256, 0, stream>>>(part, bf2 + (size_t)i*1024, x);
  }

  layernorm_k<1><<<1024, 256, 0, stream>>>(x, dout);
}

// Round 4
// 535.854 us; speedup vs baseline: 1.0751x; 1.0751x over previous
//
#include <hip/hip_runtime.h>

typedef unsigned short u16;
typedef __attribute__((ext_vector_type(8))) unsigned short u16x8;
typedef __attribute__((ext_vector_type(4))) unsigned short u16x4;
typedef __attribute__((ext_vector_type(4))) float f32x4;

#define DEVI __device__ __forceinline__

// ---------------- helpers ----------------
DEVI u16 f2bf(float f){
  unsigned u = __float_as_uint(f);
  u += 0x7FFFu + ((u >> 16) & 1u);      // round-to-nearest-even
  return (u16)(u >> 16);
}

DEVI void gload16(const void* g, void* l){
  __builtin_amdgcn_global_load_lds((const __attribute__((address_space(1))) void*)g,
                                   (__attribute__((address_space(3))) void*)l, 16, 0, 0);
}

DEVI float wave_sum(float v){
#pragma unroll
  for (int o = 32; o; o >>= 1) v += __shfl_xor(v, o, 64);
  return v;
}

#define MFMA16(a,b,c) __builtin_amdgcn_mfma_f32_16x16x32_bf16((a),(b),(c),0,0,0)

// ---------------- elementwise convert f32 -> bf16 ----------------
__global__ __launch_bounds__(256) void f32_to_bf16_k(const float* __restrict__ in,
                                                     u16* __restrict__ out, int n4){
  int i = blockIdx.x * 256 + threadIdx.x;
  if (i < n4){
    float4 v = ((const float4*)in)[i];
    u16x4 o = { f2bf(v.x), f2bf(v.y), f2bf(v.z), f2bf(v.w) };
    ((u16x4*)out)[i] = o;
  }
}

// ---------------- transpose f32 [R][C] -> bf16 [C][R], z-batched ----------------
__global__ __launch_bounds__(256) void trans_f32_bf16_k(const float* __restrict__ in0,
                                                        u16* __restrict__ out0, int R, int C){
  __shared__ u16 tile[32][33];
  const float* in = in0 + (size_t)blockIdx.z * R * C;
  u16* out = out0 + (size_t)blockIdx.z * R * C;
  const int c0 = blockIdx.x * 32, r0 = blockIdx.y * 32;
  const int tx = threadIdx.x & 31, ty = threadIdx.x >> 5;
#pragma unroll
  for (int k = 0; k < 4; k++)
    tile[ty + k*8][tx] = f2bf(in[(size_t)(r0 + ty + k*8) * C + c0 + tx]);
  __syncthreads();
#pragma unroll
  for (int k = 0; k < 4; k++)
    out[(size_t)(c0 + ty + k*8) * R + r0 + tx] = tile[tx][ty + k*8];
}

// ---------------- V transpose: bf16 [B*T][N*H] -> [B][N][H][T], all layers ----
__global__ __launch_bounds__(256) void vtrans_k(const u16* __restrict__ V0, u16* __restrict__ Vt0){
  __shared__ u16 tile[32][33];
  const int t0 = blockIdx.x * 32;
  const int h0 = blockIdx.y * 32;
  const int z = blockIdx.z, l = z >> 5, bn = z & 31;
  const int b = bn >> 4, n = bn & 15;
  const u16* V = V0 + (size_t)l * 1048576;
  u16* Vt = Vt0 + (size_t)l * 1048576;
  const int tx = threadIdx.x & 31, ty = threadIdx.x >> 5;
#pragma unroll
  for (int k = 0; k < 4; k++)
    tile[ty + k*8][tx] = V[(size_t)(b*512 + t0 + ty + k*8) * 1024 + n*64 + h0 + tx];
  __syncthreads();
#pragma unroll
  for (int k = 0; k < 4; k++)
    Vt[(size_t)((b*16 + n)*64 + h0 + ty + k*8) * 512 + t0 + tx] = tile[tx][ty + k*8];
}

// ---------------- layernorm: rows of 1024, (x-m)/(std+eps), bf16 out ----------
__global__ __launch_bounds__(256) void layernorm_k(const float* __restrict__ in, u16* __restrict__ outp){
  const int row = blockIdx.x;
  const int tid = threadIdx.x;
  const float4 v = ((const float4*)(in + (size_t)row * 1024))[tid];
  __shared__ float sb[8];
  const int wid = tid >> 6, lane = tid & 63;
  float s = wave_sum(v.x + v.y + v.z + v.w);
  if (lane == 0) sb[wid] = s;
  __syncthreads();
  const float mean = (sb[0] + sb[1] + sb[2] + sb[3]) * (1.0f / 1024.0f);
  const float dx = v.x - mean, dy = v.y - mean, dz = v.z - mean, dw = v.w - mean;
  float q = wave_sum(dx*dx + dy*dy + dz*dz + dw*dw);
  if (lane == 0) sb[4 + wid] = q;
  __syncthreads();
  const float sd = sqrtf((sb[4] + sb[5] + sb[6] + sb[7]) * (1.0f / 1024.0f));
  const float inv = 1.0f / (sd + 1e-6f);
  u16x4 o = { f2bf(dx*inv), f2bf(dy*inv), f2bf(dz*inv), f2bf(dw*inv) };
  ((u16x4*)outp)[(size_t)row * 256 + tid] = o;
}

// ---------------- time-bias MLP: qs[l][b,f,t], z = layer ----------------
__global__ __launch_bounds__(256) void qsbias_k(const float* __restrict__ dist,
    const float* __restrict__ Wth0, const float* __restrict__ bth0,
    const float* __restrict__ Wto0, const float* __restrict__ bto0,
    float* __restrict__ qs0){
  const int ly = blockIdx.y;
  const float* Wth = Wth0 + ly*32;
  const float* bth = bth0 + ly*32;
  const float* Wto = Wto0 + ly*32;
  float* qs = qs0 + (size_t)ly * 524288;
  const int idx = blockIdx.x * 256 + threadIdx.x;        // over B*F*T/4
  float4 s4 = ((const float4*)dist)[idx];
  float sv[4] = { s4.x, s4.y, s4.z, s4.w };
  float r[4];
  const float b0 = bto0[ly];
#pragma unroll
  for (int c = 0; c < 4; c++) r[c] = b0;
#pragma unroll
  for (int k = 0; k < 32; k++){
    const float wk = Wth[k], bk = bth[k], ok = Wto[k];
#pragma unroll
    for (int c = 0; c < 4; c++){
      float h = fmaxf(sv[c] * wk + bk, 0.0f);
      r[c] += h * ok;
    }
  }
  ((float4*)qs)[idx] = make_float4(r[0], r[1], r[2], r[3]);
}

// ---------------- 128x128 GEMM core, BK=64, 2-phase LDS double-buffer ---------
// C[M][Nd] = A[M][Krange] @ Bt[Nd][Krange]^T. 4 waves (2x2), each 64x64.
// T2 swizzle: linear gload_lds dest + inverse-swizzled global source chunk,
// reads XOR back (rule 21). MODE 0: bf16  3: bf16 relu(+bias)  5: f32 partial
template<int MODE>
DEVI void gemm128_core(const u16* A, int lda, const u16* Bt, int ldb,
                       int Klen, int Nd, void* Cout,
                       const float* bias, float scale,
                       u16* Als, u16* Bls, int row0, int col0){
  const int tid = threadIdx.x;
  const int wid = tid >> 6, lane = tid & 63;
  const int wm = wid >> 1, wn = wid & 1;
  const int lrow = lane & 15, g = lane >> 4, e7 = lane & 7;
  f32x4 acc[4][4] = {};

  const int scol = ((lane & 7) ^ ((lane >> 3) & 7)) * 8;   // inverse-swizzled src chunk
  const u16* Ag = A + (size_t)(row0 + wid*8 + (lane >> 3)) * lda + scol;
  const u16* Bg = Bt + (size_t)(col0 + wid*8 + (lane >> 3)) * ldb + scol;
  const int dst0 = wid * 512;

  const int nt = Klen >> 6;

#define STAGE128(buf, k0)                                                     \
  {                                                                           \
    _Pragma("unroll")                                                         \
    for (int q = 0; q < 4; q++){                                              \
      gload16(Ag + (size_t)q*32*lda + (k0), Als + (buf)*8192 + dst0 + q*2048);\
      gload16(Bg + (size_t)q*32*ldb + (k0), Bls + (buf)*8192 + dst0 + q*2048);\
    }                                                                         \
  }

  STAGE128(0, 0);
  __syncthreads();                       // compiler drains vmcnt before barrier

  for (int t = 0; t < nt; t++){
    const int cur = t & 1;
    if (t + 1 < nt) STAGE128(cur ^ 1, (t + 1) << 6);   // prefetch overlaps MFMA
    const u16* Ab = Als + cur * 8192;
    const u16* Bb = Bls + cur * 8192;
#pragma unroll
    for (int ks = 0; ks < 2; ks++){
      const int sl = (((ks << 2) + g) ^ e7) << 3;
      u16x8 av[4], bv[4];
#pragma unroll
      for (int mi = 0; mi < 4; mi++)
        av[mi] = *(const u16x8*)(Ab + (wm*64 + mi*16 + lrow) * 64 + sl);
#pragma unroll
      for (int ni = 0; ni < 4; ni++)
        bv[ni] = *(const u16x8*)(Bb + (wn*64 + ni*16 + lrow) * 64 + sl);
#pragma unroll
      for (int mi = 0; mi < 4; mi++)
#pragma unroll
        for (int ni = 0; ni < 4; ni++)
          acc[mi][ni] = MFMA16(av[mi], bv[ni], acc[mi][ni]);
    }
    __syncthreads();
  }
#undef STAGE128

#pragma unroll
  for (int mi = 0; mi < 4; mi++){
#pragma unroll
    for (int ni = 0; ni < 4; ni++){
      const int col = col0 + wn*64 + ni*16 + lrow;
#pragma unroll
      for (int j = 0; j < 4; j++){
        const int row = row0 + wm*64 + mi*16 + g*4 + j;
        float v = acc[mi][ni][j];
        if (MODE == 3) v = fmaxf(v + bias[col], 0.0f);
        if (MODE == 0 || MODE == 3)
          ((u16*)Cout)[(size_t)row * Nd + col] = f2bf(v);
        else
          ((float*)Cout)[(size_t)row * Nd + col] = v;
      }
    }
  }
}

template<int MODE>
__global__ __launch_bounds__(256) void gemm128_k(const u16* __restrict__ A, int lda,
    const u16* __restrict__ Bt, int ldb, int Klen, int Nd, void* __restrict__ Cout,
    const float* __restrict__ bias, float scale){
  __shared__ __align__(16) u16 Als[2 * 8192];
  __shared__ __align__(16) u16 Bls[2 * 8192];
  gemm128_core<MODE>(A, lda, Bt, ldb, Klen, Nd, Cout, bias, scale,
                     Als, Bls, blockIdx.y * 128, blockIdx.x * 128);
}

// K,V projections for ALL layers in one dispatch: z in [0,8), layer = z>>1
__global__ __launch_bounds__(256) void gemmKV_k(const u16* __restrict__ encb,
    const u16* __restrict__ Wkt, const u16* __restrict__ Wvt,
    u16* __restrict__ Kb, u16* __restrict__ Vb){
  __shared__ __align__(16) u16 Als[2 * 8192];
  __shared__ __align__(16) u16 Bls[2 * 8192];
  const int z = blockIdx.z, l = z >> 1;
  const u16* Bt = ((z & 1) ? Wvt : Wkt) + (size_t)l * 1048576;
  u16* out = ((z & 1) ? Vb : Kb) + (size_t)l * 1048576;
  gemm128_core<0>(encb, 1024, Bt, 1024, 1024, 1024, out, nullptr, 1.0f,
                  Als, Bls, blockIdx.y * 128, blockIdx.x * 128);
}

// split-K=4 GEMM into f32 partials (Nd=1024 always)
__global__ __launch_bounds__(256) void gemm_splitk_k(const u16* __restrict__ A, int lda,
    const u16* __restrict__ Bt, int ldb, int Klen, float* __restrict__ part){
  __shared__ __align__(16) u16 Als[2 * 8192];
  __shared__ __align__(16) u16 Bls[2 * 8192];
  const int z = blockIdx.z;
  gemm128_core<5>(A + (size_t)z * Klen, lda, Bt + (size_t)z * Klen, ldb, Klen, 1024,
                  part + (size_t)z * 1048576, nullptr, 1.0f,
                  Als, Bls, blockIdx.y * 128, blockIdx.x * 128);
}

// ---------------- reduce kernels ----------------
// Qb = bf16( scale * sum(part) )
__global__ __launch_bounds__(256) void reduce4_bf16_k(const float* __restrict__ part,
                                                      u16* __restrict__ out, float scale){
  const int idx = blockIdx.x * 256 + threadIdx.x;
  float4 p0 = ((const float4*)part)[idx];
  float4 p1 = ((const float4*)(part + 1048576))[idx];
  float4 p2 = ((const float4*)(part + 2097152))[idx];
  float4 p3 = ((const float4*)(part + 3145728))[idx];
  u16x4 o = { f2bf((p0.x + p1.x + p2.x + p3.x) * scale),
              f2bf((p0.y + p1.y + p2.y + p3.y) * scale),
              f2bf((p0.z + p1.z + p2.z + p3.z) * scale),
              f2bf((p0.w + p1.w + p2.w + p3.w) * scale) };
  ((u16x4*)out)[idx] = o;
}

// x += sum(part) [+ bias]; then LN(x) -> xn (bf16) or dout (f32, LAST)
// BIAS: add bias[col]. One block per row (1024 rows), 256 thr x f32x4.
template<int BIAS, int LAST>
__global__ __launch_bounds__(256) void reduce_ln_k(const float* __restrict__ part,
    const float* __restrict__ bias, float* __restrict__ x, u16* __restrict__ xn,
    float* __restrict__ dout){
  const int row = blockIdx.x, tid = threadIdx.x;
  const size_t idx = (size_t)row * 256 + tid;
  float4 v = ((const float4*)x)[idx];
  float4 p0 = ((const float4*)part)[idx];
  float4 p1 = ((const float4*)(part + 1048576))[idx];
  float4 p2 = ((const float4*)(part + 2097152))[idx];
  float4 p3 = ((const float4*)(part + 3145728))[idx];
  v.x += p0.x + p1.x + p2.x + p3.x;
  v.y += p0.y + p1.y + p2.y + p3.y;
  v.z += p0.z + p1.z + p2.z + p3.z;
  v.w += p0.w + p1.w + p2.w + p3.w;
  if (BIAS){
    const float4 b = *(const float4*)(bias + tid * 4);
    v.x += b.x; v.y += b.y; v.z += b.z; v.w += b.w;
  }
  if (!LAST) ((float4*)x)[idx] = v;        // residual carried forward

  __shared__ float sb[8];
  const int wid = tid >> 6, lane = tid & 63;
  float s = wave_sum(v.x + v.y + v.z + v.w);
  if (lane == 0) sb[wid] = s;
  __syncthreads();
  const float mean = (sb[0] + sb[1] + sb[2] + sb[3]) * (1.0f / 1024.0f);
  const float dx = v.x - mean, dy = v.y - mean, dz = v.z - mean, dw = v.w - mean;
  float q = wave_sum(dx*dx + dy*dy + dz*dz + dw*dw);
  if (lane == 0) sb[4 + wid] = q;
  __syncthreads();
  const float sd = sqrtf((sb[4] + sb[5] + sb[6] + sb[7]) * (1.0f / 1024.0f));
  const float inv = 1.0f / (sd + 1e-6f);
  if (LAST){
    ((float4*)dout)[idx] = make_float4(dx*inv, dy*inv, dz*inv, dw*inv);
  } else {
    u16x4 o = { f2bf(dx*inv), f2bf(dy*inv), f2bf(dz*inv), f2bf(dw*inv) };
    ((u16x4*)xn)[idx] = o;
  }
}

// ---------------- fused flash attention ----------------
// grid (n=16, ftile=8, b=2); 4 waves, wave w owns 16 q-rows.
// S^T = mfma(K, Q^T): lane holds S[fw+l15][t]; softmax row is lane-local in l15.
// P -> per-wave LDS (swizzled), PV = mfma(P, V^T) with V^T frags from L2.
__global__ __launch_bounds__(256, 1) void attn_k(const u16* __restrict__ Q,
    const u16* __restrict__ Kb, const u16* __restrict__ Vt,
    const float* __restrict__ qs, const float* __restrict__ abias,
    u16* __restrict__ aout){
  const int n = blockIdx.x, f0 = blockIdx.y * 64, b = blockIdx.z;
  const int w = threadIdx.x >> 6, lane = threadIdx.x & 63;
  const int l15 = lane & 15, g = lane >> 4, e7 = lane & 7;
  const int fw = f0 + w * 16;
  __shared__ __align__(16) u16 Pl[4][16 * 512];   // 64 KB, per-wave private
  u16* pw = &Pl[w][0];

  // Q fragments (B-operand): lane holds Q[fw+l15][k]
  const u16* qp = Q + ((size_t)b*512 + fw + l15) * 1024 + n*64 + g*8;
  const u16x8 qf0 = *(const u16x8*)qp;
  const u16x8 qf1 = *(const u16x8*)(qp + 32);

  // QK^T: acc[tf] holds S[fw+l15][tf*16 + g*4 + j]
  f32x4 acc[32];
  const u16* kp = Kb + ((size_t)b*512 + l15) * 1024 + n*64 + g*8;
#pragma unroll
  for (int tf = 0; tf < 32; tf++){
    u16x8 k0 = *(const u16x8*)(kp + (size_t)tf*16*1024);
    u16x8 k1 = *(const u16x8*)(kp + (size_t)tf*16*1024 + 32);
    f32x4 z = {0.f, 0.f, 0.f, 0.f};
    z = MFMA16(k0, qf0, z);
    acc[tf] = MFMA16(k1, qf1, z);
  }

  // + qs bias + attn bias, row max
  const float* qsp = qs + ((size_t)b*512 + fw + l15) * 512 + g*4;
  const float* abp = abias + (size_t)b*512 + g*4;
  float m = -3.0e38f;
#pragma unroll
  for (int tf = 0; tf < 32; tf++){
    float4 qv = *(const float4*)(qsp + tf*16);
    float4 av = *(const float4*)(abp + tf*16);
    acc[tf][0] += qv.x + av.x;
    acc[tf][1] += qv.y + av.y;
    acc[tf][2] += qv.z + av.z;
    acc[tf][3] += qv.w + av.w;
    m = fmaxf(m, fmaxf(fmaxf(acc[tf][0], acc[tf][1]), fmaxf(acc[tf][2], acc[tf][3])));
  }
  m = fmaxf(m, __shfl_xor(m, 16, 64));
  m = fmaxf(m, __shfl_xor(m, 32, 64));

  float s = 0.f;
#pragma unroll
  for (int tf = 0; tf < 32; tf++){
#pragma unroll
    for (int j = 0; j < 4; j++){
      float e = __expf(acc[tf][j] - m);
      acc[tf][j] = e; s += e;
    }
  }
  s += __shfl_xor(s, 16, 64);
  s += __shfl_xor(s, 32, 64);
  const float inv = 1.0f / s;
  float invj[4];
#pragma unroll
  for (int j = 0; j < 4; j++) invj[j] = __shfl(inv, g*4 + j, 64);  // inv for row g*4+j

  // store unnormalized P (<=1) row-major [16][512] bf16, chunk-swizzled
#pragma unroll
  for (int tf = 0; tf < 32; tf++){
    const int chunk = tf*2 + (g >> 1);
    const int boff = (l15 << 10) + ((chunk ^ e7) << 4) + ((g & 1) << 3);
    u16x4 pk = { f2bf(acc[tf][0]), f2bf(acc[tf][1]), f2bf(acc[tf][2]), f2bf(acc[tf][3]) };
    *(u16x4*)((char*)pw + boff) = pk;
  }

  // PV: O[f][h] = P[f][:] @ V[:][h];  V^T frags direct from global (L2-resident)
  f32x4 oacc[4] = {};
  const u16* vp = Vt + ((size_t)(b*16 + n)*64 + l15) * 512 + g*8;
  for (int kk = 0; kk < 16; kk++){
    u16x8 pa = *(const u16x8*)((char*)pw + (l15 << 10) + ((((kk << 2) + g) ^ e7) << 4));
#pragma unroll
    for (int nf = 0; nf < 4; nf++){
      u16x8 vb = *(const u16x8*)(vp + (size_t)nf*16*512 + kk*32);
      oacc[nf] = MFMA16(pa, vb, oacc[nf]);
    }
  }

  u16* op = aout + ((size_t)b*512 + fw + g*4) * 1024 + n*64 + l15;
#pragma unroll
  for (int nf = 0; nf < 4; nf++)
#pragma unroll
    for (int j = 0; j < 4; j++)
      op[(size_t)j*1024 + nf*16] = f2bf(oacc[nf][j] * invj[j]);
}

// ---------------- host ----------------
extern "C" void kernel_launch(void* const* d_in, const int* in_sizes, int n_in,
                              void* d_out, int out_size, void* d_ws, size_t ws_size,
                              hipStream_t stream){
  const float* dec_in   = (const float*)d_in[0];
  const float* enc      = (const float*)d_in[1];
  const float* dist     = (const float*)d_in[3];
  const float* abias    = (const float*)d_in[5];
  const float* Wq  = (const float*)d_in[6];
  const float* Wk  = (const float*)d_in[7];
  const float* Wv  = (const float*)d_in[8];
  const float* Wo  = (const float*)d_in[9];
  const float* Wth = (const float*)d_in[10];
  const float* bth = (const float*)d_in[11];
  const float* Wto = (const float*)d_in[12];
  const float* bto = (const float*)d_in[13];
  const float* Wf1 = (const float*)d_in[14];
  const float* bf1 = (const float*)d_in[15];
  const float* Wf2 = (const float*)d_in[16];
  const float* bf2 = (const float*)d_in[17];
  float* dout = (float*)d_out;

  char* wp = (char*)d_ws;
  auto alloc = [&](size_t n) -> char* {
    char* p = wp; wp += (n + 255) & ~(size_t)255; return p;
  };
  float* x     = (float*)alloc((size_t)1048576 * 4);
  u16*  xn     = (u16*)alloc((size_t)1048576 * 2);
  u16*  encb   = (u16*)alloc((size_t)1048576 * 2);
  u16*  Wqt    = (u16*)alloc((size_t)4194304 * 2);    // 4 layers
  u16*  Wkt    = (u16*)alloc((size_t)4194304 * 2);
  u16*  Wvt    = (u16*)alloc((size_t)4194304 * 2);
  u16*  Wot    = (u16*)alloc((size_t)4194304 * 2);
  u16*  Wf1t   = (u16*)alloc((size_t)16777216 * 2);   // 4 layers
  u16*  Wf2t   = (u16*)alloc((size_t)16777216 * 2);
  u16*  Kb     = (u16*)alloc((size_t)4194304 * 2);    // 4 layers
  u16*  Vb     = (u16*)alloc((size_t)4194304 * 2);
  u16*  Vt     = (u16*)alloc((size_t)4194304 * 2);
  u16*  Qb     = (u16*)alloc((size_t)1048576 * 2);
  float* qs    = (float*)alloc((size_t)2097152 * 4);  // 4 layers
  u16*  aout   = (u16*)alloc((size_t)1048576 * 2);
  u16*  ffh    = (u16*)alloc((size_t)4194304 * 2);
  float* part  = (float*)alloc((size_t)4194304 * 4);  // 4x 1024x1024 f32

  // ---- upfront: everything that doesn't depend on x ----
  hipMemcpyAsync(x, dec_in, (size_t)1048576 * 4, hipMemcpyDeviceToDevice, stream);
  f32_to_bf16_k<<<1024, 256, 0, stream>>>(enc, encb, 262144);

  trans_f32_bf16_k<<<dim3(32, 32, 4), 256, 0, stream>>>(Wq, Wqt, 1024, 1024);
  trans_f32_bf16_k<<<dim3(32, 32, 4), 256, 0, stream>>>(Wk, Wkt, 1024, 1024);
  trans_f32_bf16_k<<<dim3(32, 32, 4), 256, 0, stream>>>(Wv, Wvt, 1024, 1024);
  trans_f32_bf16_k<<<dim3(32, 32, 4), 256, 0, stream>>>(Wo, Wot, 1024, 1024);
  trans_f32_bf16_k<<<dim3(128, 32, 4), 256, 0, stream>>>(Wf1, Wf1t, 1024, 4096);
  trans_f32_bf16_k<<<dim3(32, 128, 4), 256, 0, stream>>>(Wf2, Wf2t, 4096, 1024);

  qsbias_k<<<dim3(512, 4), 256, 0, stream>>>(dist, Wth, bth, Wto, bto, qs);

  // K,V projections for all 4 layers (512 blocks, 2 blocks/CU)
  gemmKV_k<<<dim3(8, 8, 8), 256, 0, stream>>>(encb, Wkt, Wvt, Kb, Vb);
  vtrans_k<<<dim3(16, 2, 128), 256, 0, stream>>>(Vb, Vt);

  layernorm_k<<<1024, 256, 0, stream>>>(x, xn);

  // ---- per-layer serial chain: 8 dispatches ----
  for (int i = 0; i < 4; i++){
    const size_t wo = (size_t)i * 1048576;

    // Q projection (split-K=4) + reduce with 1/8 scale
    gemm_splitk_k<<<dim3(8, 8, 4), 256, 0, stream>>>(xn, 1024, Wqt + wo, 1024, 256, part);
    reduce4_bf16_k<<<1024, 256, 0, stream>>>(part, Qb, 0.125f);

    // fused attention (logits + biases + softmax + PV)
    attn_k<<<dim3(16, 8, 2), 256, 0, stream>>>(Qb, Kb + wo, Vt + wo,
                                               qs + (size_t)i * 524288, abias, aout);

    // O projection (split-K=4) + fused residual+LN
    gemm_splitk_k<<<dim3(8, 8, 4), 256, 0, stream>>>(aout, 1024, Wot + wo, 1024, 256, part);
    reduce_ln_k<0, 0><<<1024, 256, 0, stream>>>(part, nullptr, x, xn, nullptr);

    // FFN
    gemm128_k<3><<<dim3(32, 8), 256, 0, stream>>>(xn, 1024, Wf1t + (size_t)i*4194304, 1024,
                                                  1024, 4096, ffh, bf1 + (size_t)i*4096, 1.0f);
    gemm_splitk_k<<<dim3(8, 8, 4), 256, 0, stream>>>(ffh, 4096, Wf2t + (size_t)i*4194304, 4096,
                                                     1024, part);
    if (i < 3)
      reduce_ln_k<1, 0><<<1024, 256, 0, stream>>>(part, bf2 + (size_t)i*1024, x, xn, nullptr);
    else
      reduce_ln_k<1, 1><<<1024, 256, 0, stream>>>(part, bf2 + (size_t)i*1024, x, nullptr, dout);
  }
}

// Round 5
// 489.116 us; speedup vs baseline: 1.1778x; 1.0956x over previous
//
#include <hip/hip_runtime.h>

typedef unsigned short u16;
typedef __attribute__((ext_vector_type(8))) unsigned short u16x8;
typedef __attribute__((ext_vector_type(4))) unsigned short u16x4;
typedef __attribute__((ext_vector_type(4))) float f32x4;

#define DEVI __device__ __forceinline__

// ---------------- helpers ----------------
DEVI u16 f2bf(float f){
  unsigned u = __float_as_uint(f);
  u += 0x7FFFu + ((u >> 16) & 1u);      // round-to-nearest-even
  return (u16)(u >> 16);
}

DEVI void gload16(const void* g, void* l){
  __builtin_amdgcn_global_load_lds((const __attribute__((address_space(1))) void*)g,
                                   (__attribute__((address_space(3))) void*)l, 16, 0, 0);
}

DEVI float wave_sum(float v){
#pragma unroll
  for (int o = 32; o; o >>= 1) v += __shfl_xor(v, o, 64);
  return v;
}

#define MFMA16(a,b,c) __builtin_amdgcn_mfma_f32_16x16x32_bf16((a),(b),(c),0,0,0)

// ---------------- elementwise convert f32 -> bf16 ----------------
__global__ __launch_bounds__(256) void f32_to_bf16_k(const float* __restrict__ in,
                                                     u16* __restrict__ out, int n4){
  int i = blockIdx.x * 256 + threadIdx.x;
  if (i < n4){
    float4 v = ((const float4*)in)[i];
    u16x4 o = { f2bf(v.x), f2bf(v.y), f2bf(v.z), f2bf(v.w) };
    ((u16x4*)out)[i] = o;
  }
}

// ---------------- transpose f32 [R][C] -> bf16 [C][R], z-batched ----------------
__global__ __launch_bounds__(256) void trans_f32_bf16_k(const float* __restrict__ in0,
                                                        u16* __restrict__ out0, int R, int C){
  __shared__ u16 tile[32][33];
  const float* in = in0 + (size_t)blockIdx.z * R * C;
  u16* out = out0 + (size_t)blockIdx.z * R * C;
  const int c0 = blockIdx.x * 32, r0 = blockIdx.y * 32;
  const int tx = threadIdx.x & 31, ty = threadIdx.x >> 5;
#pragma unroll
  for (int k = 0; k < 4; k++)
    tile[ty + k*8][tx] = f2bf(in[(size_t)(r0 + ty + k*8) * C + c0 + tx]);
  __syncthreads();
#pragma unroll
  for (int k = 0; k < 4; k++)
    out[(size_t)(c0 + ty + k*8) * R + r0 + tx] = tile[tx][ty + k*8];
}

// QKVO transposes in ONE dispatch: z in [0,16), sel = z>>2, layer = z&3
__global__ __launch_bounds__(256) void trans4_f32_bf16_k(
    const float* __restrict__ Wq, const float* __restrict__ Wk,
    const float* __restrict__ Wv, const float* __restrict__ Wo,
    u16* __restrict__ Wqt, u16* __restrict__ Wkt,
    u16* __restrict__ Wvt, u16* __restrict__ Wot){
  __shared__ u16 tile[32][33];
  const int z = blockIdx.z, sel = z >> 2, l = z & 3;
  const float* in = (sel == 0 ? Wq : sel == 1 ? Wk : sel == 2 ? Wv : Wo) + (size_t)l * 1048576;
  u16* out = (sel == 0 ? Wqt : sel == 1 ? Wkt : sel == 2 ? Wvt : Wot) + (size_t)l * 1048576;
  const int c0 = blockIdx.x * 32, r0 = blockIdx.y * 32;
  const int tx = threadIdx.x & 31, ty = threadIdx.x >> 5;
#pragma unroll
  for (int k = 0; k < 4; k++)
    tile[ty + k*8][tx] = f2bf(in[(size_t)(r0 + ty + k*8) * 1024 + c0 + tx]);
  __syncthreads();
#pragma unroll
  for (int k = 0; k < 4; k++)
    out[(size_t)(c0 + ty + k*8) * 1024 + r0 + tx] = tile[tx][ty + k*8];
}

// ---------------- V transpose: bf16 [B*T][N*H] -> [B][N][H][T], all layers ----
__global__ __launch_bounds__(256) void vtrans_k(const u16* __restrict__ V0, u16* __restrict__ Vt0){
  __shared__ u16 tile[32][33];
  const int t0 = blockIdx.x * 32;
  const int h0 = blockIdx.y * 32;
  const int z = blockIdx.z, l = z >> 5, bn = z & 31;
  const int b = bn >> 4, n = bn & 15;
  const u16* V = V0 + (size_t)l * 1048576;
  u16* Vt = Vt0 + (size_t)l * 1048576;
  const int tx = threadIdx.x & 31, ty = threadIdx.x >> 5;
#pragma unroll
  for (int k = 0; k < 4; k++)
    tile[ty + k*8][tx] = V[(size_t)(b*512 + t0 + ty + k*8) * 1024 + n*64 + h0 + tx];
  __syncthreads();
#pragma unroll
  for (int k = 0; k < 4; k++)
    Vt[(size_t)((b*16 + n)*64 + h0 + ty + k*8) * 512 + t0 + tx] = tile[tx][ty + k*8];
}

// ---------------- layernorm: rows of 1024, (x-m)/(std+eps), bf16 out ----------
__global__ __launch_bounds__(256) void layernorm_k(const float* __restrict__ in, u16* __restrict__ outp){
  const int row = blockIdx.x;
  const int tid = threadIdx.x;
  const float4 v = ((const float4*)(in + (size_t)row * 1024))[tid];
  __shared__ float sb[8];
  const int wid = tid >> 6, lane = tid & 63;
  float s = wave_sum(v.x + v.y + v.z + v.w);
  if (lane == 0) sb[wid] = s;
  __syncthreads();
  const float mean = (sb[0] + sb[1] + sb[2] + sb[3]) * (1.0f / 1024.0f);
  const float dx = v.x - mean, dy = v.y - mean, dz = v.z - mean, dw = v.w - mean;
  float q = wave_sum(dx*dx + dy*dy + dz*dz + dw*dw);
  if (lane == 0) sb[4 + wid] = q;
  __syncthreads();
  const float sd = sqrtf((sb[4] + sb[5] + sb[6] + sb[7]) * (1.0f / 1024.0f));
  const float inv = 1.0f / (sd + 1e-6f);
  u16x4 o = { f2bf(dx*inv), f2bf(dy*inv), f2bf(dz*inv), f2bf(dw*inv) };
  ((u16x4*)outp)[(size_t)row * 256 + tid] = o;
}

// ---------------- time-bias MLP: qs[l][b,f,t], y = layer ----------------
__global__ __launch_bounds__(256) void qsbias_k(const float* __restrict__ dist,
    const float* __restrict__ Wth0, const float* __restrict__ bth0,
    const float* __restrict__ Wto0, const float* __restrict__ bto0,
    float* __restrict__ qs0){
  const int ly = blockIdx.y;
  const float* Wth = Wth0 + ly*32;
  const float* bth = bth0 + ly*32;
  const float* Wto = Wto0 + ly*32;
  float* qs = qs0 + (size_t)ly * 524288;
  const int idx = blockIdx.x * 256 + threadIdx.x;        // over B*F*T/4
  float4 s4 = ((const float4*)dist)[idx];
  float sv[4] = { s4.x, s4.y, s4.z, s4.w };
  float r[4];
  const float b0 = bto0[ly];
#pragma unroll
  for (int c = 0; c < 4; c++) r[c] = b0;
#pragma unroll
  for (int k = 0; k < 32; k++){
    const float wk = Wth[k], bk = bth[k], ok = Wto[k];
#pragma unroll
    for (int c = 0; c < 4; c++){
      float h = fmaxf(sv[c] * wk + bk, 0.0f);
      r[c] += h * ok;
    }
  }
  ((float4*)qs)[idx] = make_float4(r[0], r[1], r[2], r[3]);
}

// ---------------- 128xBN GEMM core, BK=64, 2-phase LDS double-buffer ---------
// C[M][Nd] = A[M][Krange] @ Bt[Nd][Krange]^T. 4 waves (2x2), each 64x(BN/2).
// T2 swizzle: linear gload_lds dest + inverse-swizzled global source chunk,
// reads XOR back (rule 21). MODE 0: bf16  3: bf16 relu(+bias)  5: f32 partial
template<int MODE, int BN>
DEVI void gemm128_core(const u16* A, int lda, const u16* Bt, int ldb,
                       int Klen, int Nd, void* Cout,
                       const float* bias, float scale,
                       u16* Als, u16* Bls, int row0, int col0){
  constexpr int WN = BN / 2, FN = BN / 32;
  constexpr int BSZ = BN * 64;           // B-buffer elements per phase
  const int tid = threadIdx.x;
  const int wid = tid >> 6, lane = tid & 63;
  const int wm = wid >> 1, wn = wid & 1;
  const int lrow = lane & 15, g = lane >> 4, e7 = lane & 7;
  f32x4 acc[4][FN] = {};

  const int scol = ((lane & 7) ^ ((lane >> 3) & 7)) * 8;   // inverse-swizzled src chunk
  const u16* Ag = A + (size_t)(row0 + wid*8 + (lane >> 3)) * lda + scol;
  const u16* Bg = Bt + (size_t)(col0 + wid*8 + (lane >> 3)) * ldb + scol;
  const int dst0 = wid * 512;

  const int nt = Klen >> 6;

#define STAGE128(buf, k0)                                                     \
  {                                                                           \
    _Pragma("unroll")                                                         \
    for (int q = 0; q < 4; q++)                                               \
      gload16(Ag + (size_t)q*32*lda + (k0), Als + (buf)*8192 + dst0 + q*2048);\
    _Pragma("unroll")                                                         \
    for (int q = 0; q < BN/32; q++)                                           \
      gload16(Bg + (size_t)q*32*ldb + (k0), Bls + (buf)*BSZ + dst0 + q*2048); \
  }

  STAGE128(0, 0);
  __syncthreads();                       // compiler drains vmcnt before barrier

  for (int t = 0; t < nt; t++){
    const int cur = t & 1;
    if (t + 1 < nt) STAGE128(cur ^ 1, (t + 1) << 6);   // prefetch overlaps MFMA
    const u16* Ab = Als + cur * 8192;
    const u16* Bb = Bls + cur * BSZ;
#pragma unroll
    for (int ks = 0; ks < 2; ks++){
      const int sl = (((ks << 2) + g) ^ e7) << 3;
      u16x8 av[4], bv[FN];
#pragma unroll
      for (int mi = 0; mi < 4; mi++)
        av[mi] = *(const u16x8*)(Ab + (wm*64 + mi*16 + lrow) * 64 + sl);
#pragma unroll
      for (int ni = 0; ni < FN; ni++)
        bv[ni] = *(const u16x8*)(Bb + (wn*WN + ni*16 + lrow) * 64 + sl);
#pragma unroll
      for (int mi = 0; mi < 4; mi++)
#pragma unroll
        for (int ni = 0; ni < FN; ni++)
          acc[mi][ni] = MFMA16(av[mi], bv[ni], acc[mi][ni]);
    }
    __syncthreads();
  }
#undef STAGE128

#pragma unroll
  for (int mi = 0; mi < 4; mi++){
#pragma unroll
    for (int ni = 0; ni < FN; ni++){
      const int col = col0 + wn*WN + ni*16 + lrow;
#pragma unroll
      for (int j = 0; j < 4; j++){
        const int row = row0 + wm*64 + mi*16 + g*4 + j;
        float v = acc[mi][ni][j];
        if (MODE == 3) v = fmaxf(v + bias[col], 0.0f);
        if (MODE == 0 || MODE == 3)
          ((u16*)Cout)[(size_t)row * Nd + col] = f2bf(v);
        else
          ((float*)Cout)[(size_t)row * Nd + col] = v;
      }
    }
  }
}

template<int MODE>
__global__ __launch_bounds__(256) void gemm128_k(const u16* __restrict__ A, int lda,
    const u16* __restrict__ Bt, int ldb, int Klen, int Nd, void* __restrict__ Cout,
    const float* __restrict__ bias, float scale){
  __shared__ __align__(16) u16 Als[2 * 8192];
  __shared__ __align__(16) u16 Bls[2 * 4096];
  gemm128_core<MODE, 64>(A, lda, Bt, ldb, Klen, Nd, Cout, bias, scale,
                         Als, Bls, blockIdx.y * 128, blockIdx.x * 64);
}

// K,V projections for ALL layers in one dispatch: z in [0,8), layer = z>>1
__global__ __launch_bounds__(256) void gemmKV_k(const u16* __restrict__ encb,
    const u16* __restrict__ Wkt, const u16* __restrict__ Wvt,
    u16* __restrict__ Kb, u16* __restrict__ Vb){
  __shared__ __align__(16) u16 Als[2 * 8192];
  __shared__ __align__(16) u16 Bls[2 * 4096];
  const int z = blockIdx.z, l = z >> 1;
  const u16* Bt = ((z & 1) ? Wvt : Wkt) + (size_t)l * 1048576;
  u16* out = ((z & 1) ? Vb : Kb) + (size_t)l * 1048576;
  gemm128_core<0, 64>(encb, 1024, Bt, 1024, 1024, 1024, out, nullptr, 1.0f,
                      Als, Bls, blockIdx.y * 128, blockIdx.x * 64);
}

// split-K=4 GEMM into f32 partials (Nd=1024 always)
__global__ __launch_bounds__(256) void gemm_splitk_k(const u16* __restrict__ A, int lda,
    const u16* __restrict__ Bt, int ldb, int Klen, float* __restrict__ part){
  __shared__ __align__(16) u16 Als[2 * 8192];
  __shared__ __align__(16) u16 Bls[2 * 4096];
  const int z = blockIdx.z;
  gemm128_core<5, 64>(A + (size_t)z * Klen, lda, Bt + (size_t)z * Klen, ldb, Klen, 1024,
                      part + (size_t)z * 1048576, nullptr, 1.0f,
                      Als, Bls, blockIdx.y * 128, blockIdx.x * 64);
}

// ---------------- reduce + layernorm ----------------
// x += sum(part) [+ bias]; then LN(x) -> xn (bf16) or dout (f32, LAST)
template<int BIAS, int LAST>
__global__ __launch_bounds__(256) void reduce_ln_k(const float* __restrict__ part,
    const float* __restrict__ bias, float* __restrict__ x, u16* __restrict__ xn,
    float* __restrict__ dout){
  const int row = blockIdx.x, tid = threadIdx.x;
  const size_t idx = (size_t)row * 256 + tid;
  float4 v = ((const float4*)x)[idx];
  float4 p0 = ((const float4*)part)[idx];
  float4 p1 = ((const float4*)(part + 1048576))[idx];
  float4 p2 = ((const float4*)(part + 2097152))[idx];
  float4 p3 = ((const float4*)(part + 3145728))[idx];
  v.x += p0.x + p1.x + p2.x + p3.x;
  v.y += p0.y + p1.y + p2.y + p3.y;
  v.z += p0.z + p1.z + p2.z + p3.z;
  v.w += p0.w + p1.w + p2.w + p3.w;
  if (BIAS){
    const float4 b = *(const float4*)(bias + tid * 4);
    v.x += b.x; v.y += b.y; v.z += b.z; v.w += b.w;
  }
  if (!LAST) ((float4*)x)[idx] = v;        // residual carried forward

  __shared__ float sb[8];
  const int wid = tid >> 6, lane = tid & 63;
  float s = wave_sum(v.x + v.y + v.z + v.w);
  if (lane == 0) sb[wid] = s;
  __syncthreads();
  const float mean = (sb[0] + sb[1] + sb[2] + sb[3]) * (1.0f / 1024.0f);
  const float dx = v.x - mean, dy = v.y - mean, dz = v.z - mean, dw = v.w - mean;
  float q = wave_sum(dx*dx + dy*dy + dz*dz + dw*dw);
  if (lane == 0) sb[4 + wid] = q;
  __syncthreads();
  const float sd = sqrtf((sb[4] + sb[5] + sb[6] + sb[7]) * (1.0f / 1024.0f));
  const float inv = 1.0f / (sd + 1e-6f);
  if (LAST){
    ((float4*)dout)[idx] = make_float4(dx*inv, dy*inv, dz*inv, dw*inv);
  } else {
    u16x4 o = { f2bf(dx*inv), f2bf(dy*inv), f2bf(dz*inv), f2bf(dw*inv) };
    ((u16x4*)xn)[idx] = o;
  }
}

// ---------------- fused flash attention (+ Q split-K reduce fused) ----------
// grid (n=16, ftile=8, b=2); 4 waves, wave w owns 16 q-rows.
// Q-frags built by summing the 4 f32 split-K partials in-register (x 1/8).
// S^T = mfma(K, Q^T): lane holds S[fw+l15][t]; softmax row is lane-local in l15.
// P -> per-wave LDS (swizzled), PV = mfma(P, V^T) with V^T frags from L2.
__global__ __launch_bounds__(256, 1) void attn_k(const float* __restrict__ partQ,
    const u16* __restrict__ Kb, const u16* __restrict__ Vt,
    const float* __restrict__ qs, const float* __restrict__ abias,
    u16* __restrict__ aout){
  const int n = blockIdx.x, f0 = blockIdx.y * 64, b = blockIdx.z;
  const int w = threadIdx.x >> 6, lane = threadIdx.x & 63;
  const int l15 = lane & 15, g = lane >> 4, e7 = lane & 7;
  const int fw = f0 + w * 16;
  __shared__ __align__(16) u16 Pl[4][16 * 512];   // 64 KB, per-wave private
  u16* pw = &Pl[w][0];

  // Q fragments (B-operand): sum 4 split-K partials, scale by H^-0.5
  u16x8 qf0, qf1;
  {
    const float* pq = partQ + ((size_t)b*512 + fw + l15) * 1024 + n*64 + g*8;
    float q0[8] = {0,0,0,0,0,0,0,0}, q1[8] = {0,0,0,0,0,0,0,0};
#pragma unroll
    for (int z = 0; z < 4; z++){
      const float* p = pq + (size_t)z * 1048576;
#pragma unroll
      for (int e = 0; e < 8; e++){ q0[e] += p[e]; q1[e] += p[e + 32]; }
    }
#pragma unroll
    for (int e = 0; e < 8; e++){
      qf0[e] = f2bf(q0[e] * 0.125f);
      qf1[e] = f2bf(q1[e] * 0.125f);
    }
  }

  // QK^T: acc[tf] holds S[fw+l15][tf*16 + g*4 + j]
  f32x4 acc[32];
  const u16* kp = Kb + ((size_t)b*512 + l15) * 1024 + n*64 + g*8;
#pragma unroll
  for (int tf = 0; tf < 32; tf++){
    u16x8 k0 = *(const u16x8*)(kp + (size_t)tf*16*1024);
    u16x8 k1 = *(const u16x8*)(kp + (size_t)tf*16*1024 + 32);
    f32x4 z = {0.f, 0.f, 0.f, 0.f};
    z = MFMA16(k0, qf0, z);
    acc[tf] = MFMA16(k1, qf1, z);
  }

  // + qs bias + attn bias, row max
  const float* qsp = qs + ((size_t)b*512 + fw + l15) * 512 + g*4;
  const float* abp = abias + (size_t)b*512 + g*4;
  float m = -3.0e38f;
#pragma unroll
  for (int tf = 0; tf < 32; tf++){
    float4 qv = *(const float4*)(qsp + tf*16);
    float4 av = *(const float4*)(abp + tf*16);
    acc[tf][0] += qv.x + av.x;
    acc[tf][1] += qv.y + av.y;
    acc[tf][2] += qv.z + av.z;
    acc[tf][3] += qv.w + av.w;
    m = fmaxf(m, fmaxf(fmaxf(acc[tf][0], acc[tf][1]), fmaxf(acc[tf][2], acc[tf][3])));
  }
  m = fmaxf(m, __shfl_xor(m, 16, 64));
  m = fmaxf(m, __shfl_xor(m, 32, 64));

  float s = 0.f;
#pragma unroll
  for (int tf = 0; tf < 32; tf++){
#pragma unroll
    for (int j = 0; j < 4; j++){
      float e = __expf(acc[tf][j] - m);
      acc[tf][j] = e; s += e;
    }
  }
  s += __shfl_xor(s, 16, 64);
  s += __shfl_xor(s, 32, 64);
  const float inv = 1.0f / s;
  float invj[4];
#pragma unroll
  for (int j = 0; j < 4; j++) invj[j] = __shfl(inv, g*4 + j, 64);  // inv for row g*4+j

  // store unnormalized P (<=1) row-major [16][512] bf16, chunk-swizzled
#pragma unroll
  for (int tf = 0; tf < 32; tf++){
    const int chunk = tf*2 + (g >> 1);
    const int boff = (l15 << 10) + ((chunk ^ e7) << 4) + ((g & 1) << 3);
    u16x4 pk = { f2bf(acc[tf][0]), f2bf(acc[tf][1]), f2bf(acc[tf][2]), f2bf(acc[tf][3]) };
    *(u16x4*)((char*)pw + boff) = pk;
  }

  // PV: O[f][h] = P[f][:] @ V[:][h];  V^T frags direct from global (L2-resident)
  f32x4 oacc[4] = {};
  const u16* vp = Vt + ((size_t)(b*16 + n)*64 + l15) * 512 + g*8;
  for (int kk = 0; kk < 16; kk++){
    u16x8 pa = *(const u16x8*)((char*)pw + (l15 << 10) + ((((kk << 2) + g) ^ e7) << 4));
#pragma unroll
    for (int nf = 0; nf < 4; nf++){
      u16x8 vb = *(const u16x8*)(vp + (size_t)nf*16*512 + kk*32);
      oacc[nf] = MFMA16(pa, vb, oacc[nf]);
    }
  }

  u16* op = aout + ((size_t)b*512 + fw + g*4) * 1024 + n*64 + l15;
#pragma unroll
  for (int nf = 0; nf < 4; nf++)
#pragma unroll
    for (int j = 0; j < 4; j++)
      op[(size_t)j*1024 + nf*16] = f2bf(oacc[nf][j] * invj[j]);
}

// ---------------- host ----------------
extern "C" void kernel_launch(void* const* d_in, const int* in_sizes, int n_in,
                              void* d_out, int out_size, void* d_ws, size_t ws_size,
                              hipStream_t stream){
  const float* dec_in   = (const float*)d_in[0];
  const float* enc      = (const float*)d_in[1];
  const float* dist     = (const float*)d_in[3];
  const float* abias    = (const float*)d_in[5];
  const float* Wq  = (const float*)d_in[6];
  const float* Wk  = (const float*)d_in[7];
  const float* Wv  = (const float*)d_in[8];
  const float* Wo  = (const float*)d_in[9];
  const float* Wth = (const float*)d_in[10];
  const float* bth = (const float*)d_in[11];
  const float* Wto = (const float*)d_in[12];
  const float* bto = (const float*)d_in[13];
  const float* Wf1 = (const float*)d_in[14];
  const float* bf1 = (const float*)d_in[15];
  const float* Wf2 = (const float*)d_in[16];
  const float* bf2 = (const float*)d_in[17];
  float* dout = (float*)d_out;

  char* wp = (char*)d_ws;
  auto alloc = [&](size_t n) -> char* {
    char* p = wp; wp += (n + 255) & ~(size_t)255; return p;
  };
  float* x     = (float*)alloc((size_t)1048576 * 4);
  u16*  xn     = (u16*)alloc((size_t)1048576 * 2);
  u16*  encb   = (u16*)alloc((size_t)1048576 * 2);
  u16*  Wqt    = (u16*)alloc((size_t)4194304 * 2);    // 4 layers
  u16*  Wkt    = (u16*)alloc((size_t)4194304 * 2);
  u16*  Wvt    = (u16*)alloc((size_t)4194304 * 2);
  u16*  Wot    = (u16*)alloc((size_t)4194304 * 2);
  u16*  Wf1t   = (u16*)alloc((size_t)16777216 * 2);   // 4 layers
  u16*  Wf2t   = (u16*)alloc((size_t)16777216 * 2);
  u16*  Kb     = (u16*)alloc((size_t)4194304 * 2);    // 4 layers
  u16*  Vb     = (u16*)alloc((size_t)4194304 * 2);
  u16*  Vt     = (u16*)alloc((size_t)4194304 * 2);
  float* qs    = (float*)alloc((size_t)2097152 * 4);  // 4 layers
  u16*  aout   = (u16*)alloc((size_t)1048576 * 2);
  u16*  ffh    = (u16*)alloc((size_t)4194304 * 2);
  float* part  = (float*)alloc((size_t)4194304 * 4);  // 4x 1024x1024 f32

  // ---- upfront: everything that doesn't depend on x ----
  hipMemcpyAsync(x, dec_in, (size_t)1048576 * 4, hipMemcpyDeviceToDevice, stream);
  f32_to_bf16_k<<<1024, 256, 0, stream>>>(enc, encb, 262144);

  trans4_f32_bf16_k<<<dim3(32, 32, 16), 256, 0, stream>>>(Wq, Wk, Wv, Wo, Wqt, Wkt, Wvt, Wot);
  trans_f32_bf16_k<<<dim3(128, 32, 4), 256, 0, stream>>>(Wf1, Wf1t, 1024, 4096);
  trans_f32_bf16_k<<<dim3(32, 128, 4), 256, 0, stream>>>(Wf2, Wf2t, 4096, 1024);

  qsbias_k<<<dim3(512, 4), 256, 0, stream>>>(dist, Wth, bth, Wto, bto, qs);

  // K,V projections for all 4 layers (1024 blocks, ~3 blocks/CU capacity)
  gemmKV_k<<<dim3(16, 8, 8), 256, 0, stream>>>(encb, Wkt, Wvt, Kb, Vb);
  vtrans_k<<<dim3(16, 2, 128), 256, 0, stream>>>(Vb, Vt);

  layernorm_k<<<1024, 256, 0, stream>>>(x, xn);

  // ---- per-layer serial chain: 7 dispatches ----
  for (int i = 0; i < 4; i++){
    const size_t wo = (size_t)i * 1048576;

    // Q projection (split-K=4, 512 blocks); reduce fused into attn
    gemm_splitk_k<<<dim3(16, 8, 4), 256, 0, stream>>>(xn, 1024, Wqt + wo, 1024, 256, part);

    // fused attention (Q-reduce + logits + biases + softmax + PV)
    attn_k<<<dim3(16, 8, 2), 256, 0, stream>>>(part, Kb + wo, Vt + wo,
                                               qs + (size_t)i * 524288, abias, aout);

    // O projection (split-K=4) + fused residual+LN
    gemm_splitk_k<<<dim3(16, 8, 4), 256, 0, stream>>>(aout, 1024, Wot + wo, 1024, 256, part);
    reduce_ln_k<0, 0><<<1024, 256, 0, stream>>>(part, nullptr, x, xn, nullptr);

    // FFN
    gemm128_k<3><<<dim3(64, 8), 256, 0, stream>>>(xn, 1024, Wf1t + (size_t)i*4194304, 1024,
                                                  1024, 4096, ffh, bf1 + (size_t)i*4096, 1.0f);
    gemm_splitk_k<<<dim3(16, 8, 4), 256, 0, stream>>>(ffh, 4096, Wf2t + (size_t)i*4194304, 4096,
                                                      1024, part);
    if (i < 3)
      reduce_ln_k<1, 0><<<1024, 256, 0, stream>>>(part, bf2 + (size_t)i*1024, x, xn, nullptr);
    else
      reduce_ln_k<1, 1><<<1024, 256, 0, stream>>>(part, bf2 + (size_t)i*1024, x, nullptr, dout);
  }
}

// Round 6
// 454.501 us; speedup vs baseline: 1.2675x; 1.0762x over previous
//
#include <hip/hip_runtime.h>

typedef unsigned short u16;
typedef __attribute__((ext_vector_type(8))) unsigned short u16x8;
typedef __attribute__((ext_vector_type(4))) unsigned short u16x4;
typedef __attribute__((ext_vector_type(4))) float f32x4;

#define DEVI __device__ __forceinline__

// ---------------- helpers ----------------
DEVI u16 f2bf(float f){
  unsigned u = __float_as_uint(f);
  u += 0x7FFFu + ((u >> 16) & 1u);      // round-to-nearest-even
  return (u16)(u >> 16);
}

DEVI void gload16(const void* g, void* l){
  __builtin_amdgcn_global_load_lds((const __attribute__((address_space(1))) void*)g,
                                   (__attribute__((address_space(3))) void*)l, 16, 0, 0);
}

DEVI float wave_sum(float v){
#pragma unroll
  for (int o = 32; o; o >>= 1) v += __shfl_xor(v, o, 64);
  return v;
}

#define MFMA16(a,b,c) __builtin_amdgcn_mfma_f32_16x16x32_bf16((a),(b),(c),0,0,0)

// ---------------- prep: ALL weight transposes + enc convert, one dispatch ----
// flat grid: [0,16384) QKVO  [16384,32768) Wf1  [32768,49152) Wf2
//            [49152,50176) enc f32->bf16
__global__ __launch_bounds__(256) void prep_k(
    const float* __restrict__ Wq, const float* __restrict__ Wk,
    const float* __restrict__ Wv, const float* __restrict__ Wo,
    const float* __restrict__ Wf1, const float* __restrict__ Wf2,
    const float* __restrict__ enc,
    u16* __restrict__ Wqt, u16* __restrict__ Wkt,
    u16* __restrict__ Wvt, u16* __restrict__ Wot,
    u16* __restrict__ Wf1t, u16* __restrict__ Wf2t,
    u16* __restrict__ encb){
  __shared__ u16 tile[32][33];
  const int t = blockIdx.x;
  if (t >= 49152){                       // enc convert (no transpose)
    const int i = (t - 49152) * 256 + threadIdx.x;
    float4 v = ((const float4*)enc)[i];
    u16x4 o = { f2bf(v.x), f2bf(v.y), f2bf(v.z), f2bf(v.w) };
    ((u16x4*)encb)[i] = o;
    return;
  }
  const float* in; u16* out; int C, R, r0, c0;
  if (t < 16384){
    const int mat = t >> 10, ti = t & 1023, sel = mat >> 2, l = mat & 3;
    in  = (sel == 0 ? Wq : sel == 1 ? Wk : sel == 2 ? Wv : Wo) + (size_t)l * 1048576;
    out = (sel == 0 ? Wqt : sel == 1 ? Wkt : sel == 2 ? Wvt : Wot) + (size_t)l * 1048576;
    R = 1024; C = 1024; r0 = (ti >> 5) * 32; c0 = (ti & 31) * 32;
  } else if (t < 32768){
    const int t2 = t - 16384, mat = t2 >> 12, ti = t2 & 4095;
    in = Wf1 + (size_t)mat * 4194304; out = Wf1t + (size_t)mat * 4194304;
    R = 1024; C = 4096; r0 = (ti >> 7) * 32; c0 = (ti & 127) * 32;
  } else {
    const int t2 = t - 32768, mat = t2 >> 12, ti = t2 & 4095;
    in = Wf2 + (size_t)mat * 4194304; out = Wf2t + (size_t)mat * 4194304;
    R = 4096; C = 1024; r0 = (ti >> 5) * 32; c0 = (ti & 31) * 32;
  }
  const int tx = threadIdx.x & 31, ty = threadIdx.x >> 5;
#pragma unroll
  for (int k = 0; k < 4; k++)
    tile[ty + k*8][tx] = f2bf(in[(size_t)(r0 + ty + k*8) * C + c0 + tx]);
  __syncthreads();
#pragma unroll
  for (int k = 0; k < 4; k++)
    out[(size_t)(c0 + ty + k*8) * R + r0 + tx] = tile[tx][ty + k*8];
}

// ---------------- layernorm: rows of 1024, (x-m)/(std+eps), bf16 out ----------
__global__ __launch_bounds__(256) void layernorm_k(const float* __restrict__ in, u16* __restrict__ outp){
  const int row = blockIdx.x;
  const int tid = threadIdx.x;
  const float4 v = ((const float4*)(in + (size_t)row * 1024))[tid];
  __shared__ float sb[8];
  const int wid = tid >> 6, lane = tid & 63;
  float s = wave_sum(v.x + v.y + v.z + v.w);
  if (lane == 0) sb[wid] = s;
  __syncthreads();
  const float mean = (sb[0] + sb[1] + sb[2] + sb[3]) * (1.0f / 1024.0f);
  const float dx = v.x - mean, dy = v.y - mean, dz = v.z - mean, dw = v.w - mean;
  float q = wave_sum(dx*dx + dy*dy + dz*dz + dw*dw);
  if (lane == 0) sb[4 + wid] = q;
  __syncthreads();
  const float sd = sqrtf((sb[4] + sb[5] + sb[6] + sb[7]) * (1.0f / 1024.0f));
  const float inv = 1.0f / (sd + 1e-6f);
  u16x4 o = { f2bf(dx*inv), f2bf(dy*inv), f2bf(dz*inv), f2bf(dw*inv) };
  ((u16x4*)outp)[(size_t)row * 256 + tid] = o;
}

// ---------------- time-bias MLP: qs[l][b,f,t], y = layer ----------------
__global__ __launch_bounds__(256) void qsbias_k(const float* __restrict__ dist,
    const float* __restrict__ Wth0, const float* __restrict__ bth0,
    const float* __restrict__ Wto0, const float* __restrict__ bto0,
    float* __restrict__ qs0){
  const int ly = blockIdx.y;
  const float* Wth = Wth0 + ly*32;
  const float* bth = bth0 + ly*32;
  const float* Wto = Wto0 + ly*32;
  float* qs = qs0 + (size_t)ly * 524288;
  const int idx = blockIdx.x * 256 + threadIdx.x;        // over B*F*T/4
  float4 s4 = ((const float4*)dist)[idx];
  float sv[4] = { s4.x, s4.y, s4.z, s4.w };
  float r[4];
  const float b0 = bto0[ly];
#pragma unroll
  for (int c = 0; c < 4; c++) r[c] = b0;
#pragma unroll
  for (int k = 0; k < 32; k++){
    const float wk = Wth[k], bk = bth[k], ok = Wto[k];
#pragma unroll
    for (int c = 0; c < 4; c++){
      float h = fmaxf(sv[c] * wk + bk, 0.0f);
      r[c] += h * ok;
    }
  }
  ((float4*)qs)[idx] = make_float4(r[0], r[1], r[2], r[3]);
}

// ---------------- 128xBN GEMM core, BK=64, 2-phase LDS double-buffer ---------
// C[M][Nd] = A[M][Krange] @ Bt[Nd][Krange]^T. 4 waves (2x2), each 64x(BN/2).
// T2 swizzle: linear gload_lds dest + inverse-swizzled global source chunk,
// reads XOR back (rule 21). MODE 0: bf16  3: bf16 relu(+bias)  5: f32 partial
// MODE 6: V^T scatter (row = n*64+h, col = b*512+t -> Vt[(b*16+n)*64+h][t])
template<int MODE, int BN>
DEVI void gemm128_core(const u16* A, int lda, const u16* Bt, int ldb,
                       int Klen, int Nd, void* Cout,
                       const float* bias, float scale,
                       u16* Als, u16* Bls, int row0, int col0){
  constexpr int WN = BN / 2, FN = BN / 32;
  constexpr int BSZ = BN * 64;           // B-buffer elements per phase
  const int tid = threadIdx.x;
  const int wid = tid >> 6, lane = tid & 63;
  const int wm = wid >> 1, wn = wid & 1;
  const int lrow = lane & 15, g = lane >> 4, e7 = lane & 7;
  f32x4 acc[4][FN] = {};

  const int scol = ((lane & 7) ^ ((lane >> 3) & 7)) * 8;   // inverse-swizzled src chunk
  const u16* Ag = A + (size_t)(row0 + wid*8 + (lane >> 3)) * lda + scol;
  const u16* Bg = Bt + (size_t)(col0 + wid*8 + (lane >> 3)) * ldb + scol;
  const int dst0 = wid * 512;

  const int nt = Klen >> 6;

#define STAGE128(buf, k0)                                                     \
  {                                                                           \
    _Pragma("unroll")                                                         \
    for (int q = 0; q < 4; q++)                                               \
      gload16(Ag + (size_t)q*32*lda + (k0), Als + (buf)*8192 + dst0 + q*2048);\
    _Pragma("unroll")                                                         \
    for (int q = 0; q < BN/32; q++)                                           \
      gload16(Bg + (size_t)q*32*ldb + (k0), Bls + (buf)*BSZ + dst0 + q*2048); \
  }

  STAGE128(0, 0);
  __syncthreads();                       // compiler drains vmcnt before barrier

  for (int t = 0; t < nt; t++){
    const int cur = t & 1;
    if (t + 1 < nt) STAGE128(cur ^ 1, (t + 1) << 6);   // prefetch overlaps MFMA
    const u16* Ab = Als + cur * 8192;
    const u16* Bb = Bls + cur * BSZ;
#pragma unroll
    for (int ks = 0; ks < 2; ks++){
      const int sl = (((ks << 2) + g) ^ e7) << 3;
      u16x8 av[4], bv[FN];
#pragma unroll
      for (int mi = 0; mi < 4; mi++)
        av[mi] = *(const u16x8*)(Ab + (wm*64 + mi*16 + lrow) * 64 + sl);
#pragma unroll
      for (int ni = 0; ni < FN; ni++)
        bv[ni] = *(const u16x8*)(Bb + (wn*WN + ni*16 + lrow) * 64 + sl);
#pragma unroll
      for (int mi = 0; mi < 4; mi++)
#pragma unroll
        for (int ni = 0; ni < FN; ni++)
          acc[mi][ni] = MFMA16(av[mi], bv[ni], acc[mi][ni]);
    }
    __syncthreads();
  }
#undef STAGE128

#pragma unroll
  for (int mi = 0; mi < 4; mi++){
#pragma unroll
    for (int ni = 0; ni < FN; ni++){
      const int col = col0 + wn*WN + ni*16 + lrow;
#pragma unroll
      for (int j = 0; j < 4; j++){
        const int row = row0 + wm*64 + mi*16 + g*4 + j;
        float v = acc[mi][ni][j];
        if (MODE == 3) v = fmaxf(v + bias[col], 0.0f);
        if (MODE == 0 || MODE == 3)
          ((u16*)Cout)[(size_t)row * Nd + col] = f2bf(v);
        else if (MODE == 6)
          ((u16*)Cout)[(size_t)((col >> 9)*16 + (row >> 6)) * 32768
                       + (row & 63) * 512 + (col & 511)] = f2bf(v);
        else
          ((float*)Cout)[(size_t)row * Nd + col] = v;
      }
    }
  }
}

template<int MODE>
__global__ __launch_bounds__(256) void gemm128_k(const u16* __restrict__ A, int lda,
    const u16* __restrict__ Bt, int ldb, int Klen, int Nd, void* __restrict__ Cout,
    const float* __restrict__ bias, float scale){
  __shared__ __align__(16) u16 Als[2 * 8192];
  __shared__ __align__(16) u16 Bls[2 * 4096];
  gemm128_core<MODE, 64>(A, lda, Bt, ldb, Klen, Nd, Cout, bias, scale,
                         Als, Bls, blockIdx.y * 128, blockIdx.x * 64);
}

// K-proj (normal) + V-proj (transposed output) for ALL layers: z in [0,8)
__global__ __launch_bounds__(256) void gemmKV_k(const u16* __restrict__ encb,
    const u16* __restrict__ Wkt, const u16* __restrict__ Wvt,
    u16* __restrict__ Kb, u16* __restrict__ Vt){
  __shared__ __align__(16) u16 Als[2 * 8192];
  __shared__ __align__(16) u16 Bls[2 * 4096];
  const int z = blockIdx.z, l = z >> 1;
  if ((z & 1) == 0)
    gemm128_core<0, 64>(encb, 1024, Wkt + (size_t)l*1048576, 1024, 1024, 1024,
                        Kb + (size_t)l*1048576, nullptr, 1.0f,
                        Als, Bls, blockIdx.y * 128, blockIdx.x * 64);
  else   // C[h'][b*512+t] = Wvt @ encb^T, scattered into Vt[(b,n,h),t]
    gemm128_core<6, 64>(Wvt + (size_t)l*1048576, 1024, encb, 1024, 1024, 1024,
                        Vt + (size_t)l*1048576, nullptr, 1.0f,
                        Als, Bls, blockIdx.y * 128, blockIdx.x * 64);
}

// split-K=4 GEMM into f32 partials (Nd=1024 always)
__global__ __launch_bounds__(256) void gemm_splitk_k(const u16* __restrict__ A, int lda,
    const u16* __restrict__ Bt, int ldb, int Klen, float* __restrict__ part){
  __shared__ __align__(16) u16 Als[2 * 8192];
  __shared__ __align__(16) u16 Bls[2 * 4096];
  const int z = blockIdx.z;
  gemm128_core<5, 64>(A + (size_t)z * Klen, lda, Bt + (size_t)z * Klen, ldb, Klen, 1024,
                      part + (size_t)z * 1048576, nullptr, 1.0f,
                      Als, Bls, blockIdx.y * 128, blockIdx.x * 64);
}

// ---------------- reduce + layernorm ----------------
// x += sum(part) [+ bias]; then LN(x) -> xn (bf16) or dout (f32, LAST)
template<int BIAS, int LAST>
__global__ __launch_bounds__(256) void reduce_ln_k(const float* __restrict__ part,
    const float* __restrict__ bias, float* __restrict__ x, u16* __restrict__ xn,
    float* __restrict__ dout){
  const int row = blockIdx.x, tid = threadIdx.x;
  const size_t idx = (size_t)row * 256 + tid;
  float4 v = ((const float4*)x)[idx];
  float4 p0 = ((const float4*)part)[idx];
  float4 p1 = ((const float4*)(part + 1048576))[idx];
  float4 p2 = ((const float4*)(part + 2097152))[idx];
  float4 p3 = ((const float4*)(part + 3145728))[idx];
  v.x += p0.x + p1.x + p2.x + p3.x;
  v.y += p0.y + p1.y + p2.y + p3.y;
  v.z += p0.z + p1.z + p2.z + p3.z;
  v.w += p0.w + p1.w + p2.w + p3.w;
  if (BIAS){
    const float4 b = *(const float4*)(bias + tid * 4);
    v.x += b.x; v.y += b.y; v.z += b.z; v.w += b.w;
  }
  if (!LAST) ((float4*)x)[idx] = v;        // residual carried forward

  __shared__ float sb[8];
  const int wid = tid >> 6, lane = tid & 63;
  float s = wave_sum(v.x + v.y + v.z + v.w);
  if (lane == 0) sb[wid] = s;
  __syncthreads();
  const float mean = (sb[0] + sb[1] + sb[2] + sb[3]) * (1.0f / 1024.0f);
  const float dx = v.x - mean, dy = v.y - mean, dz = v.z - mean, dw = v.w - mean;
  float q = wave_sum(dx*dx + dy*dy + dz*dz + dw*dw);
  if (lane == 0) sb[4 + wid] = q;
  __syncthreads();
  const float sd = sqrtf((sb[4] + sb[5] + sb[6] + sb[7]) * (1.0f / 1024.0f));
  const float inv = 1.0f / (sd + 1e-6f);
  if (LAST){
    ((float4*)dout)[idx] = make_float4(dx*inv, dy*inv, dz*inv, dw*inv);
  } else {
    u16x4 o = { f2bf(dx*inv), f2bf(dy*inv), f2bf(dz*inv), f2bf(dw*inv) };
    ((u16x4*)xn)[idx] = o;
  }
}

// ---------------- fused flash attention (Q-projection fused in) -------------
// grid (n=16, ftile=8, b=2); 4 waves, wave w owns 16 q-rows.
// Phase A: 64x64x1024 mini-GEMM Q = xn_tile @ Wqt_slice (2-phase staged),
//          Q*H^-0.5 -> swizzled LDS tile -> per-wave B-frags.
// Phase B: S^T = mfma(K, Q^T): lane holds S[fw+l15][t]; row softmax lane-local.
// Phase C: P -> per-wave LDS (swizzled), PV = mfma(P, V^T) from L2.
__global__ __launch_bounds__(256, 1) void attn_k(const u16* __restrict__ xn,
    const u16* __restrict__ Wqt,
    const u16* __restrict__ Kb, const u16* __restrict__ Vt,
    const float* __restrict__ qs, const float* __restrict__ abias,
    u16* __restrict__ aout){
  const int n = blockIdx.x, f0 = blockIdx.y * 64, b = blockIdx.z;
  const int w = threadIdx.x >> 6, lane = threadIdx.x & 63;
  const int l15 = lane & 15, g = lane >> 4, e7 = lane & 7;
  const int fw = f0 + w * 16;
  __shared__ __align__(16) u16 Pl[4][16 * 512];   // 64 KB
  u16* pw = &Pl[w][0];

  u16x8 qf0, qf1;
  {
    // ---- Q mini-GEMM: A = xn rows [b*512+f0, +64), Bt = Wqt rows [n*64, +64)
    u16* Als = &Pl[0][0];          // 2 bufs x 4096 elems = 16 KB
    u16* Bls = &Pl[1][0];
    const int wm = w >> 1, wn = w & 1;
    f32x4 qac[2][2] = {};
    const int scol = ((lane & 7) ^ ((lane >> 3) & 7)) * 8;
    const u16* Ag = xn + (size_t)(b*512 + f0 + w*8 + (lane >> 3)) * 1024 + scol;
    const u16* Bg = Wqt + (size_t)(n*64 + w*8 + (lane >> 3)) * 1024 + scol;
    const int dq = w * 512;

#define STAGEQ(buf, k0)                                         \
    gload16(Ag + (k0),            Als + (buf)*4096 + dq);       \
    gload16(Ag + 32*1024 + (k0),  Als + (buf)*4096 + dq + 2048);\
    gload16(Bg + (k0),            Bls + (buf)*4096 + dq);       \
    gload16(Bg + 32*1024 + (k0),  Bls + (buf)*4096 + dq + 2048);

    STAGEQ(0, 0);
    __syncthreads();
    for (int t = 0; t < 16; t++){
      const int cur = t & 1;
      if (t < 15){ STAGEQ(cur ^ 1, (t + 1) << 6); }
      const u16* Ab = Als + cur * 4096;
      const u16* Bb = Bls + cur * 4096;
#pragma unroll
      for (int ks = 0; ks < 2; ks++){
        const int sl = (((ks << 2) + g) ^ e7) << 3;
        u16x8 av[2], bv[2];
#pragma unroll
        for (int mi = 0; mi < 2; mi++)
          av[mi] = *(const u16x8*)(Ab + (wm*32 + mi*16 + l15) * 64 + sl);
#pragma unroll
        for (int ni = 0; ni < 2; ni++)
          bv[ni] = *(const u16x8*)(Bb + (wn*32 + ni*16 + l15) * 64 + sl);
#pragma unroll
        for (int mi = 0; mi < 2; mi++)
#pragma unroll
          for (int ni = 0; ni < 2; ni++)
            qac[mi][ni] = MFMA16(av[mi], bv[ni], qac[mi][ni]);
      }
      __syncthreads();
    }
#undef STAGEQ

    // write Q*0.125 to swizzled 64x64 tile in Pl[2] (untouched by staging)
    u16* Qt = &Pl[2][0];
#pragma unroll
    for (int mi = 0; mi < 2; mi++)
#pragma unroll
      for (int ni = 0; ni < 2; ni++)
#pragma unroll
        for (int j = 0; j < 4; j++){
          const int r = wm*32 + mi*16 + g*4 + j;
          const int c = wn*32 + ni*16 + l15;
          const int byte = r*128 + (((c >> 3) ^ (r & 7)) << 4) + (c & 7)*2;
          *(u16*)((char*)Qt + byte) = f2bf(qac[mi][ni][j] * 0.125f);
        }
    __syncthreads();
    // read this wave's B-frags: row = w*16+l15, k-chunks g and 4+g
    const int r = w*16 + l15;
    const char* qrow = (char*)Qt + r*128;
    qf0 = *(const u16x8*)(qrow + ((g ^ (r & 7)) << 4));
    qf1 = *(const u16x8*)(qrow + (((4 + g) ^ (r & 7)) << 4));
    __syncthreads();   // all frag reads done before P-phase overwrites LDS
  }

  // QK^T: acc[tf] holds S[fw+l15][tf*16 + g*4 + j]
  f32x4 acc[32];
  const u16* kp = Kb + ((size_t)b*512 + l15) * 1024 + n*64 + g*8;
#pragma unroll
  for (int tf = 0; tf < 32; tf++){
    u16x8 k0 = *(const u16x8*)(kp + (size_t)tf*16*1024);
    u16x8 k1 = *(const u16x8*)(kp + (size_t)tf*16*1024 + 32);
    f32x4 z = {0.f, 0.f, 0.f, 0.f};
    z = MFMA16(k0, qf0, z);
    acc[tf] = MFMA16(k1, qf1, z);
  }

  // + qs bias + attn bias, row max
  const float* qsp = qs + ((size_t)b*512 + fw + l15) * 512 + g*4;
  const float* abp = abias + (size_t)b*512 + g*4;
  float m = -3.0e38f;
#pragma unroll
  for (int tf = 0; tf < 32; tf++){
    float4 qv = *(const float4*)(qsp + tf*16);
    float4 av = *(const float4*)(abp + tf*16);
    acc[tf][0] += qv.x + av.x;
    acc[tf][1] += qv.y + av.y;
    acc[tf][2] += qv.z + av.z;
    acc[tf][3] += qv.w + av.w;
    m = fmaxf(m, fmaxf(fmaxf(acc[tf][0], acc[tf][1]), fmaxf(acc[tf][2], acc[tf][3])));
  }
  m = fmaxf(m, __shfl_xor(m, 16, 64));
  m = fmaxf(m, __shfl_xor(m, 32, 64));

  float s = 0.f;
#pragma unroll
  for (int tf = 0; tf < 32; tf++){
#pragma unroll
    for (int j = 0; j < 4; j++){
      float e = __expf(acc[tf][j] - m);
      acc[tf][j] = e; s += e;
    }
  }
  s += __shfl_xor(s, 16, 64);
  s += __shfl_xor(s, 32, 64);
  const float inv = 1.0f / s;
  float invj[4];
#pragma unroll
  for (int j = 0; j < 4; j++) invj[j] = __shfl(inv, g*4 + j, 64);  // inv for row g*4+j

  // store unnormalized P (<=1) row-major [16][512] bf16, chunk-swizzled
#pragma unroll
  for (int tf = 0; tf < 32; tf++){
    const int chunk = tf*2 + (g >> 1);
    const int boff = (l15 << 10) + ((chunk ^ e7) << 4) + ((g & 1) << 3);
    u16x4 pk = { f2bf(acc[tf][0]), f2bf(acc[tf][1]), f2bf(acc[tf][2]), f2bf(acc[tf][3]) };
    *(u16x4*)((char*)pw + boff) = pk;
  }

  // PV: O[f][h] = P[f][:] @ V[:][h];  V^T frags direct from global (L2-resident)
  f32x4 oacc[4] = {};
  const u16* vp = Vt + ((size_t)(b*16 + n)*64 + l15) * 512 + g*8;
  for (int kk = 0; kk < 16; kk++){
    u16x8 pa = *(const u16x8*)((char*)pw + (l15 << 10) + ((((kk << 2) + g) ^ e7) << 4));
#pragma unroll
    for (int nf = 0; nf < 4; nf++){
      u16x8 vb = *(const u16x8*)(vp + (size_t)nf*16*512 + kk*32);
      oacc[nf] = MFMA16(pa, vb, oacc[nf]);
    }
  }

  u16* op = aout + ((size_t)b*512 + fw + g*4) * 1024 + n*64 + l15;
#pragma unroll
  for (int nf = 0; nf < 4; nf++)
#pragma unroll
    for (int j = 0; j < 4; j++)
      op[(size_t)j*1024 + nf*16] = f2bf(oacc[nf][j] * invj[j]);
}

// ---------------- host ----------------
extern "C" void kernel_launch(void* const* d_in, const int* in_sizes, int n_in,
                              void* d_out, int out_size, void* d_ws, size_t ws_size,
                              hipStream_t stream){
  const float* dec_in   = (const float*)d_in[0];
  const float* enc      = (const float*)d_in[1];
  const float* dist     = (const float*)d_in[3];
  const float* abias    = (const float*)d_in[5];
  const float* Wq  = (const float*)d_in[6];
  const float* Wk  = (const float*)d_in[7];
  const float* Wv  = (const float*)d_in[8];
  const float* Wo  = (const float*)d_in[9];
  const float* Wth = (const float*)d_in[10];
  const float* bth = (const float*)d_in[11];
  const float* Wto = (const float*)d_in[12];
  const float* bto = (const float*)d_in[13];
  const float* Wf1 = (const float*)d_in[14];
  const float* bf1 = (const float*)d_in[15];
  const float* Wf2 = (const float*)d_in[16];
  const float* bf2 = (const float*)d_in[17];
  float* dout = (float*)d_out;

  char* wp = (char*)d_ws;
  auto alloc = [&](size_t n) -> char* {
    char* p = wp; wp += (n + 255) & ~(size_t)255; return p;
  };
  float* x     = (float*)alloc((size_t)1048576 * 4);
  u16*  xn     = (u16*)alloc((size_t)1048576 * 2);
  u16*  encb   = (u16*)alloc((size_t)1048576 * 2);
  u16*  Wqt    = (u16*)alloc((size_t)4194304 * 2);    // 4 layers
  u16*  Wkt    = (u16*)alloc((size_t)4194304 * 2);
  u16*  Wvt    = (u16*)alloc((size_t)4194304 * 2);
  u16*  Wot    = (u16*)alloc((size_t)4194304 * 2);
  u16*  Wf1t   = (u16*)alloc((size_t)16777216 * 2);   // 4 layers
  u16*  Wf2t   = (u16*)alloc((size_t)16777216 * 2);
  u16*  Kb     = (u16*)alloc((size_t)4194304 * 2);    // 4 layers
  u16*  Vt     = (u16*)alloc((size_t)4194304 * 2);
  float* qs    = (float*)alloc((size_t)2097152 * 4);  // 4 layers
  u16*  aout   = (u16*)alloc((size_t)1048576 * 2);
  u16*  ffh    = (u16*)alloc((size_t)4194304 * 2);
  float* part  = (float*)alloc((size_t)4194304 * 4);  // 4x 1024x1024 f32

  // ---- upfront (5 dispatches + 1 d2d copy) ----
  hipMemcpyAsync(x, dec_in, (size_t)1048576 * 4, hipMemcpyDeviceToDevice, stream);
  prep_k<<<50176, 256, 0, stream>>>(Wq, Wk, Wv, Wo, Wf1, Wf2, enc,
                                    Wqt, Wkt, Wvt, Wot, Wf1t, Wf2t, encb);
  qsbias_k<<<dim3(512, 4), 256, 0, stream>>>(dist, Wth, bth, Wto, bto, qs);
  gemmKV_k<<<dim3(16, 8, 8), 256, 0, stream>>>(encb, Wkt, Wvt, Kb, Vt);
  layernorm_k<<<1024, 256, 0, stream>>>(x, xn);

  // ---- per-layer serial chain: 6 dispatches ----
  for (int i = 0; i < 4; i++){
    const size_t wo = (size_t)i * 1048576;

    // fused attention (Q-proj + logits + biases + softmax + PV)
    attn_k<<<dim3(16, 8, 2), 256, 0, stream>>>(xn, Wqt + wo, Kb + wo, Vt + wo,
                                               qs + (size_t)i * 524288, abias, aout);

    // O projection (split-K=4) + fused residual+LN
    gemm_splitk_k<<<dim3(16, 8, 4), 256, 0, stream>>>(aout, 1024, Wot + wo, 1024, 256, part);
    reduce_ln_k<0, 0><<<1024, 256, 0, stream>>>(part, nullptr, x, xn, nullptr);

    // FFN
    gemm128_k<3><<<dim3(64, 8), 256, 0, stream>>>(xn, 1024, Wf1t + (size_t)i*4194304, 1024,
                                                  1024, 4096, ffh, bf1 + (size_t)i*4096, 1.0f);
    gemm_splitk_k<<<dim3(16, 8, 4), 256, 0, stream>>>(ffh, 4096, Wf2t + (size_t)i*4194304, 4096,
                                                      1024, part);
    if (i < 3)
      reduce_ln_k<1, 0><<<1024, 256, 0, stream>>>(part, bf2 + (size_t)i*1024, x, xn, nullptr);
    else
      reduce_ln_k<1, 1><<<1024, 256, 0, stream>>>(part, bf2 + (size_t)i*1024, x, nullptr, dout);
  }
}